// Round 3
// baseline (1225.976 us; speedup 1.0000x reference)
//
#include <hip/hip_runtime.h>

// MSDformer: deformable conv (q) + transposed-channel attention + proj.
// fp32 throughout. R2: k_deform rebuilt (CSPLIT=2 + atomics, 8o x 4px threads,
// A in LDS as [k][o] for b128 reads, prefetch placed to hide under GEMM);
// k_qkv / k_out rebuilt on the same pattern.
constexpr int SPLITS = 24;
constexpr size_t OFF_OFS  = 0;                         // [2][18][9216]
constexpr size_t Q_OFS    = 331776;                    // [2][192][9216]
constexpr size_t K_OFS    = Q_OFS + 3538944;
constexpr size_t V_OFS    = K_OFS + 3538944;
constexpr size_t NQ_OFS   = V_OFS + 3538944;           // [2*192] inv-norms
constexpr size_t NK_OFS   = NQ_OFS + 384;
constexpr size_t PART_OFS = NK_OFS + 384;              // [24][12][1024]
constexpr size_t ATTN_OFS = PART_OFS + (size_t)SPLITS * 12 * 1024;  // [12][1024]
constexpr size_t W2_OFS   = ATTN_OFS + 12288;          // [2][192][192]

// ---------------------------------------------------------------- K0: zero q (deform accumulates atomically)
__global__ __launch_bounds__(256) void k_zero(float4* __restrict__ p, int n4) {
  int i = blockIdx.x * 256 + threadIdx.x;
  if (i < n4) p[i] = float4{0.f, 0.f, 0.f, 0.f};
}

// ---------------------------------------------------------------- K1: offset conv
__global__ __launch_bounds__(192) void k_offset_conv(
    const float* __restrict__ x, const float* __restrict__ pw,
    const float* __restrict__ pb, float* __restrict__ off)
{
  __shared__ __align__(16) float sx[4 * 10 * 100];   // [ch][row(10)][col pad 100]
  int blk = blockIdx.x;
  int b  = blk / 108;
  int r  = blk % 108;
  int o0 = (r / 12) * 2;
  int h0 = (r % 12) * 8;
  int t  = threadIdx.x;
  int prow = (4 * t) / 96;       // 0..7
  int wb   = (4 * t) % 96;       // multiple of 4
  float acc[2][4] = {};
  for (int c0 = 0; c0 < 192; c0 += 4) {
    __syncthreads();
    for (int e = t; e < 3920; e += 192) {
      int ch = e / 980, r2 = e % 980;
      int row = r2 / 98, col = r2 % 98;
      int gr = h0 + row - 1, gc = col - 1;
      float v = 0.f;
      if (gr >= 0 && gr < 96 && gc >= 0 && gc < 96)
        v = x[((b * 192 + c0 + ch) * 96 + gr) * 96 + gc];
      sx[ch * 1000 + row * 100 + col] = v;
    }
    __syncthreads();
#pragma unroll
    for (int ch = 0; ch < 4; ++ch) {
      float w0[9], w1[9];
#pragma unroll
      for (int kk = 0; kk < 9; ++kk) {   // wave-uniform -> s_load
        w0[kk] = pw[(o0 * 192 + c0 + ch) * 9 + kk];
        w1[kk] = pw[((o0 + 1) * 192 + c0 + ch) * 9 + kk];
      }
#pragma unroll
      for (int ki = 0; ki < 3; ++ki) {
        const float* base = &sx[ch * 1000 + (prow + ki) * 100 + wb];
        float4 f4 = *(const float4*)base;
        float2 f2 = *(const float2*)(base + 4);
        float xv[6] = {f4.x, f4.y, f4.z, f4.w, f2.x, f2.y};
#pragma unroll
        for (int kj = 0; kj < 3; ++kj)
#pragma unroll
          for (int p = 0; p < 4; ++p) {
            acc[0][p] += w0[ki * 3 + kj] * xv[kj + p];
            acc[1][p] += w1[ki * 3 + kj] * xv[kj + p];
          }
      }
    }
  }
  float bb0 = pb[o0], bb1 = pb[o0 + 1];
  int orow = h0 + prow;
  float4 s0 = {acc[0][0] + bb0, acc[0][1] + bb0, acc[0][2] + bb0, acc[0][3] + bb0};
  float4 s1 = {acc[1][0] + bb1, acc[1][1] + bb1, acc[1][2] + bb1, acc[1][3] + bb1};
  *(float4*)&off[((b * 18 + o0) * 96 + orow) * 96 + wb] = s0;
  *(float4*)&off[((b * 18 + o0 + 1) * 96 + orow) * 96 + wb] = s1;
}

// ---------------------------------------------------------------- K2: fused deform conv
// grid 1152 = csplit(2, interleaved) x B x 96 rows x 3 wtiles; block 192 (3 waves).
// Each block: 96 channels (48 chunks of 2), thread = 8o x 4px, atomicAdd into q.
__device__ __forceinline__ float deform_slow_sample(
    const float* __restrict__ x, const float* __restrict__ off,
    int b, int c, int n, int h, int w)
{
  int ki = n / 3, kj = n % 3;
  float ox = off[((b * 18 + n) * 96 + h) * 96 + w];
  float oy = off[((b * 18 + 9 + n) * 96 + h) * 96 + w];
  float px = (float)(h + ki) + ox;
  float py = (float)(w + kj) + oy;
  float fx = floorf(px), fy = floorf(py);
  int qx0 = max(0, min(97, (int)fx));
  int qx1 = max(0, min(97, (int)fx + 1));
  int qy0 = max(0, min(97, (int)fy));
  int qy1 = max(0, min(97, (int)fy + 1));
  float pxc = fminf(fmaxf(px, 0.f), 97.f);
  float pyc = fminf(fmaxf(py, 0.f), 97.f);
  float wx0 = 1.f + ((float)qx0 - pxc);
  float wx1 = 1.f - ((float)qx1 - pxc);
  float wy0 = 1.f + ((float)qy0 - pyc);
  float wy1 = 1.f - ((float)qy1 - pyc);
  auto xp = [&](int qx, int qy) -> float {
    int X = qx - 1, Y = qy - 1;
    return (X >= 0 && X < 96 && Y >= 0 && Y < 96)
               ? x[((b * 192 + c) * 96 + X) * 96 + Y] : 0.f;
  };
  return wx0 * wy0 * xp(qx0, qy0) + wx1 * wy1 * xp(qx1, qy1)
       + wx0 * wy1 * xp(qx0, qy1) + wx1 * wy0 * xp(qx1, qy0);
}

__global__ __launch_bounds__(192) void k_deform(
    const float* __restrict__ x, const float* __restrict__ off,
    const float* __restrict__ dw, float* __restrict__ q)
{
  __shared__ __align__(16) float4 tg[288];       // bilinear weights (lt,rb,lb,rt)
  __shared__ unsigned tq[288];                   // packed band-local idx + flag
  __shared__ float band[2 * 13 * 44];            // x band for 2 channels
  __shared__ __align__(16) float Al[18 * 196];   // A chunk [k][o], pad 196
  __shared__ __align__(16) float Bl[18 * 32];    // x_off chunk [k][pix]
  int blk = blockIdx.x;
  int cs = blk & 1;                               // channel split (interleaved)
  int r3 = blk >> 1;
  int b  = r3 / 288;
  int rr = r3 % 288;
  int h  = rr / 3;
  int w0 = (rr % 3) * 32;
  int cbase = cs * 96;
  int t  = threadIdx.x;

  // phase A: bilinear tables for 32 px x 9 taps
  for (int e = t; e < 288; e += 192) {
    int n = e >> 5, pix = e & 31;
    int ki = n / 3, kj = n % 3;
    int w = w0 + pix;
    float ox = off[((b * 18 + n) * 96 + h) * 96 + w];
    float oy = off[((b * 18 + 9 + n) * 96 + h) * 96 + w];
    float px = (float)(h + ki) + ox;
    float py = (float)(w + kj) + oy;
    float fx = floorf(px), fy = floorf(py);
    int qx0 = max(0, min(97, (int)fx));
    int qx1 = max(0, min(97, (int)fx + 1));
    int qy0 = max(0, min(97, (int)fy));
    int qy1 = max(0, min(97, (int)fy + 1));
    float pxc = fminf(fmaxf(px, 0.f), 97.f);
    float pyc = fminf(fmaxf(py, 0.f), 97.f);
    float wx0 = 1.f + ((float)qx0 - pxc);
    float wx1 = 1.f - ((float)qx1 - pxc);
    float wy0 = 1.f + ((float)qy0 - pyc);
    float wy1 = 1.f - ((float)qy1 - pyc);
    float4 g = {wx0 * wy0, wx1 * wy1, wx0 * wy1, wx1 * wy0};
    int lx0 = qx0 - h + 5, lx1 = qx1 - h + 5;     // band row = image X - (h-6)
    int ly0 = qy0 - w0 + 5, ly1 = qy1 - w0 + 5;
    unsigned flag = (lx0 >= 0 && lx1 < 13 && ly0 >= 0 && ly1 < 44) ? 1u : 0u;
    lx0 = max(0, min(12, lx0)); lx1 = max(0, min(12, lx1));
    ly0 = max(0, min(43, ly0)); ly1 = max(0, min(43, ly1));
    tg[e] = g;
    tq[e] = (unsigned)lx0 | ((unsigned)ly0 << 5) | ((unsigned)lx1 << 11)
          | ((unsigned)ly1 << 16) | (flag << 31);
  }

  // prefetch address bases (per-chunk term added later)
  int  bbase[6]; bool bval[6];
  int  abase[18];
#pragma unroll
  for (int i = 0; i < 6; ++i) {
    int e = t + i * 192;
    bval[i] = false; bbase[i] = 0;
    if (e < 1144) {
      int cc = e / 572, r2 = e % 572;
      int lx = r2 / 44, ly = r2 % 44;
      int X = h - 6 + lx, Y = w0 - 6 + ly;
      if (X >= 0 && X < 96 && Y >= 0 && Y < 96) {
        bval[i] = true;
        bbase[i] = ((b * 192 + cbase + cc) * 96 + X) * 96 + Y;
      }
    }
  }
#pragma unroll
  for (int i = 0; i < 18; ++i) {
    int e = t + i * 192;
    abase[i] = (e / 18) * 1728 + (e % 18);       // o*1728 + (cc*9+n)
  }

  float rb[6], ra[18];
#pragma unroll
  for (int i = 0; i < 6; ++i)  rb[i] = bval[i] ? x[bbase[i]] : 0.f;
#pragma unroll
  for (int i = 0; i < 18; ++i) ra[i] = dw[abase[i] + cbase * 9];

  int og = t >> 3, pg = t & 7;                    // o = og*8+i, px = pg*4+j
  float acc[8][4] = {};
  __syncthreads();                                // tables ready

  for (int lc = 0; lc < 96; lc += 2) {
    // commit prefetched regs to LDS: band + A[k][o]
#pragma unroll
    for (int i = 0; i < 6; ++i) { int e = t + i * 192; if (e < 1144) band[e] = rb[i]; }
#pragma unroll
    for (int i = 0; i < 18; ++i) {
      int e = t + i * 192;
      Al[(e % 18) * 196 + (e / 18)] = ra[i];
    }
    __syncthreads();
    // build B = x_off[k][pix] from LDS band
#pragma unroll
    for (int i = 0; i < 3; ++i) {
      int e = t + i * 192;
      int cc = e / 288, r2 = e % 288;
      int n = r2 >> 5, pix = r2 & 31;
      float4 g = tg[r2];
      unsigned u = tq[r2];
      float val;
      if (u >> 31) {
        int lx0 = u & 31, ly0 = (u >> 5) & 63, lx1 = (u >> 11) & 31, ly1 = (u >> 16) & 63;
        const float* bd = &band[cc * 572];
        val = g.x * bd[lx0 * 44 + ly0] + g.y * bd[lx1 * 44 + ly1]
            + g.z * bd[lx0 * 44 + ly1] + g.w * bd[lx1 * 44 + ly0];
      } else {
        val = deform_slow_sample(x, off, b, cbase + lc + cc, n, h, w0 + pix);
      }
      Bl[(cc * 9 + n) * 32 + pix] = val;
    }
    __syncthreads();
    // prefetch next chunk NOW: the forced vmcnt(0) at the post-GEMM barrier
    // gives it the whole GEMM (~1300cy) to land.
    if (lc + 2 < 96) {
#pragma unroll
      for (int i = 0; i < 6; ++i)  rb[i] = bval[i] ? x[bbase[i] + (lc + 2) * 9216] : 0.f;
#pragma unroll
      for (int i = 0; i < 18; ++i) ra[i] = dw[abase[i] + (cbase + lc + 2) * 9];
    }
    // GEMM: 18 k-steps, A 2xb128 + B 1xb128 + 32 FMA per thread
    const float4* B4 = (const float4*)Bl;
    const float4* A4 = (const float4*)Al;
#pragma unroll
    for (int k = 0; k < 18; ++k) {
      float4 bv = B4[k * 8 + pg];
      float4 a0 = A4[k * 49 + og * 2];
      float4 a1 = A4[k * 49 + og * 2 + 1];
      float av[8] = {a0.x, a0.y, a0.z, a0.w, a1.x, a1.y, a1.z, a1.w};
#pragma unroll
      for (int i = 0; i < 8; ++i) {
        acc[i][0] += av[i] * bv.x; acc[i][1] += av[i] * bv.y;
        acc[i][2] += av[i] * bv.z; acc[i][3] += av[i] * bv.w;
      }
    }
    __syncthreads();
  }
  size_t base = (size_t)(b * 192) * 9216 + h * 96 + w0 + pg * 4;
#pragma unroll
  for (int i = 0; i < 8; ++i)
#pragma unroll
    for (int j = 0; j < 4; ++j)
      atomicAdd(&q[base + (size_t)(og * 8 + i) * 9216 + j], acc[i][j]);
}

// ---------------------------------------------------------------- K3: k,v GEMM
// [k;v](384 x 192) @ x(192 x 18432). grid 576; block 384 (6 waves); 8o x 4px.
__global__ __launch_bounds__(384) void k_qkv(
    const float* __restrict__ x, const float* __restrict__ qkvw,
    float* __restrict__ kbuf, float* __restrict__ vbuf)
{
  __shared__ __align__(16) float Al[16 * 388];   // [k][o] pad 388
  __shared__ __align__(16) float Bl[16 * 32];
  int blk = blockIdx.x;
  int b = blk / 288;
  int pix0 = (blk % 288) * 32;
  int t = threadIdx.x;
  int og = t >> 3, pg = t & 7;                   // og 0..47
  float acc[8][4] = {};
  float ra[16], rb2[2];
#pragma unroll
  for (int i = 0; i < 16; ++i) {
    int e = t + i * 384;
    ra[i] = qkvw[(size_t)(192 + (e >> 4)) * 192 + (e & 15)];
  }
#pragma unroll
  for (int i = 0; i < 2; ++i) {
    int e = t + i * 384;
    rb2[i] = (e < 512) ? x[(size_t)(b * 192 + (e >> 5)) * 9216 + pix0 + (e & 31)] : 0.f;
  }
  for (int c0 = 0; c0 < 192; c0 += 16) {
#pragma unroll
    for (int i = 0; i < 16; ++i) {
      int e = t + i * 384;
      Al[(e & 15) * 388 + (e >> 4)] = ra[i];
    }
#pragma unroll
    for (int i = 0; i < 2; ++i) {
      int e = t + i * 384;
      if (e < 512) Bl[e] = rb2[i];
    }
    __syncthreads();
    if (c0 + 16 < 192) {
#pragma unroll
      for (int i = 0; i < 16; ++i) {
        int e = t + i * 384;
        ra[i] = qkvw[(size_t)(192 + (e >> 4)) * 192 + c0 + 16 + (e & 15)];
      }
#pragma unroll
      for (int i = 0; i < 2; ++i) {
        int e = t + i * 384;
        rb2[i] = (e < 512) ? x[(size_t)(b * 192 + c0 + 16 + (e >> 5)) * 9216 + pix0 + (e & 31)] : 0.f;
      }
    }
    const float4* B4 = (const float4*)Bl;
    const float4* A4 = (const float4*)Al;
#pragma unroll
    for (int k = 0; k < 16; ++k) {
      float4 bv = B4[k * 8 + pg];
      float4 a0 = A4[k * 97 + og * 2];
      float4 a1 = A4[k * 97 + og * 2 + 1];
      float av[8] = {a0.x, a0.y, a0.z, a0.w, a1.x, a1.y, a1.z, a1.w};
#pragma unroll
      for (int i = 0; i < 8; ++i) {
        acc[i][0] += av[i] * bv.x; acc[i][1] += av[i] * bv.y;
        acc[i][2] += av[i] * bv.z; acc[i][3] += av[i] * bv.w;
      }
    }
    __syncthreads();
  }
#pragma unroll
  for (int i = 0; i < 8; ++i) {
    int o = og * 8 + i;
    float* dst = (o < 192) ? &kbuf[(size_t)(b * 192 + o) * 9216]
                           : &vbuf[(size_t)(b * 192 + o - 192) * 9216];
    *(float4*)(dst + pix0 + pg * 4) = {acc[i][0], acc[i][1], acc[i][2], acc[i][3]};
  }
}

// ---------------------------------------------------------------- K4: inv L2 norms per (b,c) row
__global__ __launch_bounds__(256) void k_norms(
    const float* __restrict__ qbuf, const float* __restrict__ kbuf,
    float* __restrict__ nq, float* __restrict__ nk)
{
  __shared__ float red[4];
  int blk = blockIdx.x;
  int which = blk / 384, r = blk % 384;
  const float* src = (which ? kbuf : qbuf) + (size_t)r * 9216;
  int t = threadIdx.x;
  float s = 0.f;
  const float4* s4 = (const float4*)src;
  for (int i = t; i < 2304; i += 256) {
    float4 v = s4[i];
    s += v.x * v.x + v.y * v.y + v.z * v.z + v.w * v.w;
  }
#pragma unroll
  for (int o = 32; o; o >>= 1) s += __shfl_xor(s, o);
  if ((t & 63) == 0) red[t >> 6] = s;
  __syncthreads();
  if (t == 0) {
    float tot = red[0] + red[1] + red[2] + red[3];
    (which ? nk : nq)[r] = 1.f / fmaxf(sqrtf(tot), 1e-12f);
  }
}

// ---------------------------------------------------------------- K5: Gram partials (q_c . k_d)
__global__ __launch_bounds__(256) void k_gram(
    const float* __restrict__ qbuf, const float* __restrict__ kbuf,
    float* __restrict__ part)
{
  __shared__ float sq[32 * 65], sk[32 * 65];
  int blk = blockIdx.x;
  int split = blk / 12, r = blk % 12;
  int b = r / 6, hh = r % 6;
  int n0 = split * 384;
  int t = threadIdx.x;
  int c = t >> 3, dg = t & 7;
  float acc[4] = {};
  for (int sc = 0; sc < 6; ++sc) {
    __syncthreads();
    for (int i = t; i < 2048; i += 256) {
      int cc = i >> 6, j = i & 63;
      size_t g = (size_t)(b * 192 + hh * 32 + cc) * 9216 + n0 + sc * 64 + j;
      sq[cc * 65 + j] = qbuf[g];
      sk[cc * 65 + j] = kbuf[g];
    }
    __syncthreads();
#pragma unroll 8
    for (int j = 0; j < 64; ++j) {
      float qv = sq[c * 65 + j];
#pragma unroll
      for (int i2 = 0; i2 < 4; ++i2)
        acc[i2] += qv * sk[(dg * 4 + i2) * 65 + j];
    }
  }
  float* dst = &part[((size_t)split * 12 + b * 6 + hh) * 1024 + c * 32 + dg * 4];
  *(float4*)dst = {acc[0], acc[1], acc[2], acc[3]};
}

// ---------------------------------------------------------------- K6: reduce + scale + softmax(d)
__global__ __launch_bounds__(1024) void k_softmax(
    const float* __restrict__ part, const float* __restrict__ nq,
    const float* __restrict__ nk, const float* __restrict__ temp,
    float* __restrict__ attn)
{
  int bi = blockIdx.x;            // b*6+h
  int b = bi / 6, h = bi % 6;
  int t = threadIdx.x;
  int c = t >> 5, d = t & 31;
  float val = 0.f;
  for (int s = 0; s < SPLITS; ++s) val += part[((size_t)s * 12 + bi) * 1024 + t];
  val *= nq[b * 192 + h * 32 + c] * nk[b * 192 + h * 32 + d] * temp[h];
  float m = val;
#pragma unroll
  for (int o = 16; o; o >>= 1) m = fmaxf(m, __shfl_xor(m, o));
  float e = expf(val - m);
  float s = e;
#pragma unroll
  for (int o = 16; o; o >>= 1) s += __shfl_xor(s, o);
  attn[(size_t)bi * 1024 + t] = e / s;
}

// ---------------------------------------------------------------- K7: W2[b] = proj_w . blockdiag(attn)
__global__ __launch_bounds__(256) void k_w2(
    const float* __restrict__ attn, const float* __restrict__ projw,
    float* __restrict__ w2)
{
  __shared__ float sa[32 * 33];
  int bi = blockIdx.x;            // b*6+h
  int b = bi / 6, h = bi % 6;
  int t = threadIdx.x;
  for (int i = t; i < 1024; i += 256)
    sa[(i >> 5) * 33 + (i & 31)] = attn[(size_t)bi * 1024 + i];
  __syncthreads();
  for (int e = t; e < 6144; e += 256) {
    int o = e >> 5, d = e & 31;
    float s = 0.f;
#pragma unroll 8
    for (int ci = 0; ci < 32; ++ci)
      s += projw[o * 192 + h * 32 + ci] * sa[ci * 33 + d];
    w2[((size_t)b * 192 + o) * 192 + h * 32 + d] = s;
  }
}

// ---------------------------------------------------------------- K8: out = W2[b] @ v (fused attn.v + proj)
// block 384 (6 waves); per thread 4o x 4px.
__global__ __launch_bounds__(384) void k_out(
    const float* __restrict__ vbuf, const float* __restrict__ w2,
    float* __restrict__ out)
{
  __shared__ __align__(16) float Al[16 * 196];   // [k][o] pad 196
  __shared__ __align__(16) float Bl[16 * 32];
  int blk = blockIdx.x;
  int b = blk / 288;
  int pix0 = (blk % 288) * 32;
  int t = threadIdx.x;
  int og = t >> 3, pg = t & 7;                   // og 0..47 -> o = og*4+i
  float acc[4][4] = {};
  float ra[8], rb2[2];
#pragma unroll
  for (int i = 0; i < 8; ++i) {
    int e = t + i * 384;
    ra[i] = w2[(size_t)(b * 192 + (e >> 4)) * 192 + (e & 15)];
  }
#pragma unroll
  for (int i = 0; i < 2; ++i) {
    int e = t + i * 384;
    rb2[i] = (e < 512) ? vbuf[(size_t)(b * 192 + (e >> 5)) * 9216 + pix0 + (e & 31)] : 0.f;
  }
  for (int c0 = 0; c0 < 192; c0 += 16) {
#pragma unroll
    for (int i = 0; i < 8; ++i) {
      int e = t + i * 384;
      Al[(e & 15) * 196 + (e >> 4)] = ra[i];
    }
#pragma unroll
    for (int i = 0; i < 2; ++i) {
      int e = t + i * 384;
      if (e < 512) Bl[e] = rb2[i];
    }
    __syncthreads();
    if (c0 + 16 < 192) {
#pragma unroll
      for (int i = 0; i < 8; ++i) {
        int e = t + i * 384;
        ra[i] = w2[(size_t)(b * 192 + (e >> 4)) * 192 + c0 + 16 + (e & 15)];
      }
#pragma unroll
      for (int i = 0; i < 2; ++i) {
        int e = t + i * 384;
        rb2[i] = (e < 512) ? vbuf[(size_t)(b * 192 + c0 + 16 + (e >> 5)) * 9216 + pix0 + (e & 31)] : 0.f;
      }
    }
    const float4* B4 = (const float4*)Bl;
    const float4* A4 = (const float4*)Al;
#pragma unroll
    for (int k = 0; k < 16; ++k) {
      float4 bv = B4[k * 8 + pg];
      float4 a0 = A4[k * 49 + og];
      float av[4] = {a0.x, a0.y, a0.z, a0.w};
#pragma unroll
      for (int i = 0; i < 4; ++i) {
        acc[i][0] += av[i] * bv.x; acc[i][1] += av[i] * bv.y;
        acc[i][2] += av[i] * bv.z; acc[i][3] += av[i] * bv.w;
      }
    }
    __syncthreads();
  }
#pragma unroll
  for (int i = 0; i < 4; ++i) {
    int o = og * 4 + i;
    *(float4*)&out[(size_t)(b * 192 + o) * 9216 + pix0 + pg * 4]
        = {acc[i][0], acc[i][1], acc[i][2], acc[i][3]};
  }
}

// ----------------------------------------------------------------
extern "C" void kernel_launch(void* const* d_in, const int* in_sizes, int n_in,
                              void* d_out, int out_size, void* d_ws, size_t ws_size,
                              hipStream_t stream) {
  (void)in_sizes; (void)n_in; (void)out_size; (void)ws_size;
  const float* x     = (const float*)d_in[0];
  const float* pw    = (const float*)d_in[1];
  const float* pb    = (const float*)d_in[2];
  const float* dw    = (const float*)d_in[3];
  const float* qkvw  = (const float*)d_in[4];
  const float* projw = (const float*)d_in[5];
  const float* temp  = (const float*)d_in[6];
  float* ws   = (float*)d_ws;
  float* off  = ws + OFF_OFS;
  float* qb   = ws + Q_OFS;
  float* kb   = ws + K_OFS;
  float* vb   = ws + V_OFS;
  float* nq   = ws + NQ_OFS;
  float* nk   = ws + NK_OFS;
  float* part = ws + PART_OFS;
  float* attn = ws + ATTN_OFS;
  float* w2   = ws + W2_OFS;
  float* out  = (float*)d_out;

  k_zero       <<<dim3(3456), dim3(256), 0, stream>>>((float4*)qb, 884736);
  k_offset_conv<<<dim3(216),  dim3(192), 0, stream>>>(x, pw, pb, off);
  k_qkv        <<<dim3(576),  dim3(384), 0, stream>>>(x, qkvw, kb, vb);
  k_deform     <<<dim3(1152), dim3(192), 0, stream>>>(x, off, dw, qb);
  k_norms      <<<dim3(768),  dim3(256), 0, stream>>>(qb, kb, nq, nk);
  k_gram       <<<dim3(288),  dim3(256), 0, stream>>>(qb, kb, part);
  k_softmax    <<<dim3(12),   dim3(1024),0, stream>>>(part, nq, nk, temp, attn);
  k_w2         <<<dim3(12),   dim3(256), 0, stream>>>(attn, projw, w2);
  k_out        <<<dim3(576),  dim3(384), 0, stream>>>(vb, w2, out);
}

// Round 4
// 1141.161 us; speedup vs baseline: 1.0743x; 1.0743x over previous
//
#include <hip/hip_runtime.h>

// MSDformer: deformable conv (q) + transposed-channel attention + proj.
// fp32 throughout. R4: k_deform VGPR diet (no reg-prefetch; A staged as
// thread-t-owns-o=t contiguous run; band via 6 sentinel addrs) to get under
// the 128-VGPR occupancy cliff; csplit pairs placed 576 apart (same XCD).
constexpr int SPLITS = 24;
constexpr size_t OFF_OFS  = 0;                         // [2][18][9216]
constexpr size_t Q_OFS    = 331776;                    // [2][192][9216]
constexpr size_t K_OFS    = Q_OFS + 3538944;
constexpr size_t V_OFS    = K_OFS + 3538944;
constexpr size_t NQ_OFS   = V_OFS + 3538944;           // [2*192] inv-norms
constexpr size_t NK_OFS   = NQ_OFS + 384;
constexpr size_t PART_OFS = NK_OFS + 384;              // [24][12][1024]
constexpr size_t ATTN_OFS = PART_OFS + (size_t)SPLITS * 12 * 1024;  // [12][1024]
constexpr size_t W2_OFS   = ATTN_OFS + 12288;          // [2][192][192]

// ---------------------------------------------------------------- K0: zero q (deform accumulates atomically)
__global__ __launch_bounds__(256) void k_zero(float4* __restrict__ p, int n4) {
  int i = blockIdx.x * 256 + threadIdx.x;
  if (i < n4) p[i] = float4{0.f, 0.f, 0.f, 0.f};
}

// ---------------------------------------------------------------- K1: offset conv
__global__ __launch_bounds__(192) void k_offset_conv(
    const float* __restrict__ x, const float* __restrict__ pw,
    const float* __restrict__ pb, float* __restrict__ off)
{
  __shared__ __align__(16) float sx[4 * 10 * 100];   // [ch][row(10)][col pad 100]
  int blk = blockIdx.x;
  int b  = blk / 108;
  int r  = blk % 108;
  int o0 = (r / 12) * 2;
  int h0 = (r % 12) * 8;
  int t  = threadIdx.x;
  int prow = (4 * t) / 96;       // 0..7
  int wb   = (4 * t) % 96;       // multiple of 4
  float acc[2][4] = {};
  for (int c0 = 0; c0 < 192; c0 += 4) {
    __syncthreads();
    for (int e = t; e < 3920; e += 192) {
      int ch = e / 980, r2 = e % 980;
      int row = r2 / 98, col = r2 % 98;
      int gr = h0 + row - 1, gc = col - 1;
      float v = 0.f;
      if (gr >= 0 && gr < 96 && gc >= 0 && gc < 96)
        v = x[((b * 192 + c0 + ch) * 96 + gr) * 96 + gc];
      sx[ch * 1000 + row * 100 + col] = v;
    }
    __syncthreads();
#pragma unroll
    for (int ch = 0; ch < 4; ++ch) {
      float w0[9], w1[9];
#pragma unroll
      for (int kk = 0; kk < 9; ++kk) {   // wave-uniform -> s_load
        w0[kk] = pw[(o0 * 192 + c0 + ch) * 9 + kk];
        w1[kk] = pw[((o0 + 1) * 192 + c0 + ch) * 9 + kk];
      }
#pragma unroll
      for (int ki = 0; ki < 3; ++ki) {
        const float* base = &sx[ch * 1000 + (prow + ki) * 100 + wb];
        float4 f4 = *(const float4*)base;
        float2 f2 = *(const float2*)(base + 4);
        float xv[6] = {f4.x, f4.y, f4.z, f4.w, f2.x, f2.y};
#pragma unroll
        for (int kj = 0; kj < 3; ++kj)
#pragma unroll
          for (int p = 0; p < 4; ++p) {
            acc[0][p] += w0[ki * 3 + kj] * xv[kj + p];
            acc[1][p] += w1[ki * 3 + kj] * xv[kj + p];
          }
      }
    }
  }
  float bb0 = pb[o0], bb1 = pb[o0 + 1];
  int orow = h0 + prow;
  float4 s0 = {acc[0][0] + bb0, acc[0][1] + bb0, acc[0][2] + bb0, acc[0][3] + bb0};
  float4 s1 = {acc[1][0] + bb1, acc[1][1] + bb1, acc[1][2] + bb1, acc[1][3] + bb1};
  *(float4*)&off[((b * 18 + o0) * 96 + orow) * 96 + wb] = s0;
  *(float4*)&off[((b * 18 + o0 + 1) * 96 + orow) * 96 + wb] = s1;
}

// ---------------------------------------------------------------- K2: fused deform conv
// grid 1152 = csplit(2) x B x 96 rows x 3 wtiles; block 192 (3 waves).
// csplit pair = (blk, blk+576): 576%8==0 -> same XCD -> atomic lines stay local.
// No reg-prefetch (VGPR diet): occupancy provides the latency hiding.
__device__ __forceinline__ float deform_slow_sample(
    const float* __restrict__ x, const float* __restrict__ off,
    int b, int c, int n, int h, int w)
{
  int ki = n / 3, kj = n % 3;
  float ox = off[((b * 18 + n) * 96 + h) * 96 + w];
  float oy = off[((b * 18 + 9 + n) * 96 + h) * 96 + w];
  float px = (float)(h + ki) + ox;
  float py = (float)(w + kj) + oy;
  float fx = floorf(px), fy = floorf(py);
  int qx0 = max(0, min(97, (int)fx));
  int qx1 = max(0, min(97, (int)fx + 1));
  int qy0 = max(0, min(97, (int)fy));
  int qy1 = max(0, min(97, (int)fy + 1));
  float pxc = fminf(fmaxf(px, 0.f), 97.f);
  float pyc = fminf(fmaxf(py, 0.f), 97.f);
  float wx0 = 1.f + ((float)qx0 - pxc);
  float wx1 = 1.f - ((float)qx1 - pxc);
  float wy0 = 1.f + ((float)qy0 - pyc);
  float wy1 = 1.f - ((float)qy1 - pyc);
  auto xp = [&](int qx, int qy) -> float {
    int X = qx - 1, Y = qy - 1;
    return (X >= 0 && X < 96 && Y >= 0 && Y < 96)
               ? x[((b * 192 + c) * 96 + X) * 96 + Y] : 0.f;
  };
  return wx0 * wy0 * xp(qx0, qy0) + wx1 * wy1 * xp(qx1, qy1)
       + wx0 * wy1 * xp(qx0, qy1) + wx1 * wy0 * xp(qx1, qy0);
}

__global__ __launch_bounds__(192) void k_deform(
    const float* __restrict__ x, const float* __restrict__ off,
    const float* __restrict__ dw, float* __restrict__ q)
{
  __shared__ __align__(16) float4 tg[288];       // bilinear weights (lt,rb,lb,rt)
  __shared__ unsigned tq[288];                   // packed band-local idx + flag
  __shared__ float band[2 * 13 * 44];            // x band for 2 channels
  __shared__ __align__(16) float Al[18 * 196];   // A chunk [k][o], pad 196
  __shared__ __align__(16) float Bl[18 * 32];    // x_off chunk [k][pix]
  int blk = blockIdx.x;
  int cs = blk / 576;                             // csplit half (same-XCD pairing)
  int r3 = blk % 576;
  int b  = r3 / 288;
  int rr = r3 % 288;
  int h  = rr / 3;
  int w0 = (rr % 3) * 32;
  int cbase = cs * 96;
  int t  = threadIdx.x;

  // phase A: bilinear tables for 32 px x 9 taps
  for (int e = t; e < 288; e += 192) {
    int n = e >> 5, pix = e & 31;
    int ki = n / 3, kj = n % 3;
    int w = w0 + pix;
    float ox = off[((b * 18 + n) * 96 + h) * 96 + w];
    float oy = off[((b * 18 + 9 + n) * 96 + h) * 96 + w];
    float px = (float)(h + ki) + ox;
    float py = (float)(w + kj) + oy;
    float fx = floorf(px), fy = floorf(py);
    int qx0 = max(0, min(97, (int)fx));
    int qx1 = max(0, min(97, (int)fx + 1));
    int qy0 = max(0, min(97, (int)fy));
    int qy1 = max(0, min(97, (int)fy + 1));
    float pxc = fminf(fmaxf(px, 0.f), 97.f);
    float pyc = fminf(fmaxf(py, 0.f), 97.f);
    float wx0 = 1.f + ((float)qx0 - pxc);
    float wx1 = 1.f - ((float)qx1 - pxc);
    float wy0 = 1.f + ((float)qy0 - pyc);
    float wy1 = 1.f - ((float)qy1 - pyc);
    float4 g = {wx0 * wy0, wx1 * wy1, wx0 * wy1, wx1 * wy0};
    int lx0 = qx0 - h + 5, lx1 = qx1 - h + 5;     // band row = image X - (h-6)
    int ly0 = qy0 - w0 + 5, ly1 = qy1 - w0 + 5;
    unsigned flag = (lx0 >= 0 && lx1 < 13 && ly0 >= 0 && ly1 < 44) ? 1u : 0u;
    lx0 = max(0, min(12, lx0)); lx1 = max(0, min(12, lx1));
    ly0 = max(0, min(43, ly0)); ly1 = max(0, min(43, ly1));
    tg[e] = g;
    tq[e] = (unsigned)lx0 | ((unsigned)ly0 << 5) | ((unsigned)lx1 << 11)
          | ((unsigned)ly1 << 16) | (flag << 31);
  }

  // band source addresses, -1 sentinel when outside image (6 VGPRs)
  int bb[6];
#pragma unroll
  for (int i = 0; i < 6; ++i) {
    int e = t + i * 192;
    bb[i] = -1;
    if (e < 1144) {
      int cc = e / 572, r2 = e % 572;
      int lx = r2 / 44, ly = r2 % 44;
      int X = h - 6 + lx, Y = w0 - 6 + ly;
      if (X >= 0 && X < 96 && Y >= 0 && Y < 96)
        bb[i] = ((b * 192 + cbase + cc) * 96 + X) * 96 + Y;
    }
  }
  // A staging: thread t owns output channel o=t -> 18 CONSECUTIVE dw floats
  // per chunk starting at dw[t*1728 + (cbase+lc)*9].
  const float* dwt = dw + (size_t)t * 1728 + cbase * 9;

  int og = t >> 3, pg = t & 7;                    // o = og*8+i, px = pg*4+j
  float acc[8][4] = {};

  for (int lc = 0; lc < 96; lc += 2) {
    // stage band + A (global -> LDS, latency hidden by co-resident blocks)
#pragma unroll
    for (int i = 0; i < 6; ++i) {
      int e = t + i * 192;
      if (e < 1144) band[e] = (bb[i] >= 0) ? x[bb[i] + lc * 9216] : 0.f;
    }
#pragma unroll
    for (int i = 0; i < 18; ++i)
      Al[i * 196 + t] = dwt[lc * 9 + i];
    __syncthreads();
    // build B = x_off[k][pix] from LDS band
#pragma unroll
    for (int i = 0; i < 3; ++i) {
      int e = t + i * 192;
      int cc = e / 288, r2 = e % 288;
      int n = r2 >> 5, pix = r2 & 31;
      float4 g = tg[r2];
      unsigned u = tq[r2];
      float val;
      if (u >> 31) {
        int lx0 = u & 31, ly0 = (u >> 5) & 63, lx1 = (u >> 11) & 31, ly1 = (u >> 16) & 63;
        const float* bd = &band[cc * 572];
        val = g.x * bd[lx0 * 44 + ly0] + g.y * bd[lx1 * 44 + ly1]
            + g.z * bd[lx0 * 44 + ly1] + g.w * bd[lx1 * 44 + ly0];
      } else {
        val = deform_slow_sample(x, off, b, cbase + lc + cc, n, h, w0 + pix);
      }
      Bl[(cc * 9 + n) * 32 + pix] = val;
    }
    __syncthreads();
    // GEMM: 18 k-steps, A 2xb128 + B 1xb128 + 32 FMA per thread
    const float4* B4 = (const float4*)Bl;
    const float4* A4 = (const float4*)Al;
#pragma unroll
    for (int k = 0; k < 18; ++k) {
      float4 bv = B4[k * 8 + pg];
      float4 a0 = A4[k * 49 + og * 2];
      float4 a1 = A4[k * 49 + og * 2 + 1];
      float av[8] = {a0.x, a0.y, a0.z, a0.w, a1.x, a1.y, a1.z, a1.w};
#pragma unroll
      for (int i = 0; i < 8; ++i) {
        acc[i][0] += av[i] * bv.x; acc[i][1] += av[i] * bv.y;
        acc[i][2] += av[i] * bv.z; acc[i][3] += av[i] * bv.w;
      }
    }
    __syncthreads();
  }
  size_t base = (size_t)(b * 192) * 9216 + h * 96 + w0 + pg * 4;
#pragma unroll
  for (int i = 0; i < 8; ++i)
#pragma unroll
    for (int j = 0; j < 4; ++j)
      atomicAdd(&q[base + (size_t)(og * 8 + i) * 9216 + j], acc[i][j]);
}

// ---------------------------------------------------------------- K3: k,v GEMM
// [k;v](384 x 192) @ x(192 x 18432). grid 576; block 384 (6 waves); 8o x 4px.
__global__ __launch_bounds__(384) void k_qkv(
    const float* __restrict__ x, const float* __restrict__ qkvw,
    float* __restrict__ kbuf, float* __restrict__ vbuf)
{
  __shared__ __align__(16) float Al[16 * 388];   // [k][o] pad 388
  __shared__ __align__(16) float Bl[16 * 32];
  int blk = blockIdx.x;
  int b = blk / 288;
  int pix0 = (blk % 288) * 32;
  int t = threadIdx.x;
  int og = t >> 3, pg = t & 7;                   // og 0..47
  float acc[8][4] = {};
  float ra[16], rb2[2];
#pragma unroll
  for (int i = 0; i < 16; ++i) {
    int e = t + i * 384;
    ra[i] = qkvw[(size_t)(192 + (e >> 4)) * 192 + (e & 15)];
  }
#pragma unroll
  for (int i = 0; i < 2; ++i) {
    int e = t + i * 384;
    rb2[i] = (e < 512) ? x[(size_t)(b * 192 + (e >> 5)) * 9216 + pix0 + (e & 31)] : 0.f;
  }
  for (int c0 = 0; c0 < 192; c0 += 16) {
#pragma unroll
    for (int i = 0; i < 16; ++i) {
      int e = t + i * 384;
      Al[(e & 15) * 388 + (e >> 4)] = ra[i];
    }
#pragma unroll
    for (int i = 0; i < 2; ++i) {
      int e = t + i * 384;
      if (e < 512) Bl[e] = rb2[i];
    }
    __syncthreads();
    if (c0 + 16 < 192) {
#pragma unroll
      for (int i = 0; i < 16; ++i) {
        int e = t + i * 384;
        ra[i] = qkvw[(size_t)(192 + (e >> 4)) * 192 + c0 + 16 + (e & 15)];
      }
#pragma unroll
      for (int i = 0; i < 2; ++i) {
        int e = t + i * 384;
        rb2[i] = (e < 512) ? x[(size_t)(b * 192 + c0 + 16 + (e >> 5)) * 9216 + pix0 + (e & 31)] : 0.f;
      }
    }
    const float4* B4 = (const float4*)Bl;
    const float4* A4 = (const float4*)Al;
#pragma unroll
    for (int k = 0; k < 16; ++k) {
      float4 bv = B4[k * 8 + pg];
      float4 a0 = A4[k * 97 + og * 2];
      float4 a1 = A4[k * 97 + og * 2 + 1];
      float av[8] = {a0.x, a0.y, a0.z, a0.w, a1.x, a1.y, a1.z, a1.w};
#pragma unroll
      for (int i = 0; i < 8; ++i) {
        acc[i][0] += av[i] * bv.x; acc[i][1] += av[i] * bv.y;
        acc[i][2] += av[i] * bv.z; acc[i][3] += av[i] * bv.w;
      }
    }
    __syncthreads();
  }
#pragma unroll
  for (int i = 0; i < 8; ++i) {
    int o = og * 8 + i;
    float* dst = (o < 192) ? &kbuf[(size_t)(b * 192 + o) * 9216]
                           : &vbuf[(size_t)(b * 192 + o - 192) * 9216];
    *(float4*)(dst + pix0 + pg * 4) = {acc[i][0], acc[i][1], acc[i][2], acc[i][3]};
  }
}

// ---------------------------------------------------------------- K4: inv L2 norms per (b,c) row
__global__ __launch_bounds__(256) void k_norms(
    const float* __restrict__ qbuf, const float* __restrict__ kbuf,
    float* __restrict__ nq, float* __restrict__ nk)
{
  __shared__ float red[4];
  int blk = blockIdx.x;
  int which = blk / 384, r = blk % 384;
  const float* src = (which ? kbuf : qbuf) + (size_t)r * 9216;
  int t = threadIdx.x;
  float s = 0.f;
  const float4* s4 = (const float4*)src;
  for (int i = t; i < 2304; i += 256) {
    float4 v = s4[i];
    s += v.x * v.x + v.y * v.y + v.z * v.z + v.w * v.w;
  }
#pragma unroll
  for (int o = 32; o; o >>= 1) s += __shfl_xor(s, o);
  if ((t & 63) == 0) red[t >> 6] = s;
  __syncthreads();
  if (t == 0) {
    float tot = red[0] + red[1] + red[2] + red[3];
    (which ? nk : nq)[r] = 1.f / fmaxf(sqrtf(tot), 1e-12f);
  }
}

// ---------------------------------------------------------------- K5: Gram partials (q_c . k_d)
__global__ __launch_bounds__(256) void k_gram(
    const float* __restrict__ qbuf, const float* __restrict__ kbuf,
    float* __restrict__ part)
{
  __shared__ float sq[32 * 65], sk[32 * 65];
  int blk = blockIdx.x;
  int split = blk / 12, r = blk % 12;
  int b = r / 6, hh = r % 6;
  int n0 = split * 384;
  int t = threadIdx.x;
  int c = t >> 3, dg = t & 7;
  float acc[4] = {};
  for (int sc = 0; sc < 6; ++sc) {
    __syncthreads();
    for (int i = t; i < 2048; i += 256) {
      int cc = i >> 6, j = i & 63;
      size_t g = (size_t)(b * 192 + hh * 32 + cc) * 9216 + n0 + sc * 64 + j;
      sq[cc * 65 + j] = qbuf[g];
      sk[cc * 65 + j] = kbuf[g];
    }
    __syncthreads();
#pragma unroll 8
    for (int j = 0; j < 64; ++j) {
      float qv = sq[c * 65 + j];
#pragma unroll
      for (int i2 = 0; i2 < 4; ++i2)
        acc[i2] += qv * sk[(dg * 4 + i2) * 65 + j];
    }
  }
  float* dst = &part[((size_t)split * 12 + b * 6 + hh) * 1024 + c * 32 + dg * 4];
  *(float4*)dst = {acc[0], acc[1], acc[2], acc[3]};
}

// ---------------------------------------------------------------- K6: reduce + scale + softmax(d)
__global__ __launch_bounds__(1024) void k_softmax(
    const float* __restrict__ part, const float* __restrict__ nq,
    const float* __restrict__ nk, const float* __restrict__ temp,
    float* __restrict__ attn)
{
  int bi = blockIdx.x;            // b*6+h
  int b = bi / 6, h = bi % 6;
  int t = threadIdx.x;
  int c = t >> 5, d = t & 31;
  float val = 0.f;
  for (int s = 0; s < SPLITS; ++s) val += part[((size_t)s * 12 + bi) * 1024 + t];
  val *= nq[b * 192 + h * 32 + c] * nk[b * 192 + h * 32 + d] * temp[h];
  float m = val;
#pragma unroll
  for (int o = 16; o; o >>= 1) m = fmaxf(m, __shfl_xor(m, o));
  float e = expf(val - m);
  float s = e;
#pragma unroll
  for (int o = 16; o; o >>= 1) s += __shfl_xor(s, o);
  attn[(size_t)bi * 1024 + t] = e / s;
}

// ---------------------------------------------------------------- K7: W2[b] = proj_w . blockdiag(attn)
__global__ __launch_bounds__(256) void k_w2(
    const float* __restrict__ attn, const float* __restrict__ projw,
    float* __restrict__ w2)
{
  __shared__ float sa[32 * 33];
  int bi = blockIdx.x;            // b*6+h
  int b = bi / 6, h = bi % 6;
  int t = threadIdx.x;
  for (int i = t; i < 1024; i += 256)
    sa[(i >> 5) * 33 + (i & 31)] = attn[(size_t)bi * 1024 + i];
  __syncthreads();
  for (int e = t; e < 6144; e += 256) {
    int o = e >> 5, d = e & 31;
    float s = 0.f;
#pragma unroll 8
    for (int ci = 0; ci < 32; ++ci)
      s += projw[o * 192 + h * 32 + ci] * sa[ci * 33 + d];
    w2[((size_t)b * 192 + o) * 192 + h * 32 + d] = s;
  }
}

// ---------------------------------------------------------------- K8: out = W2[b] @ v (fused attn.v + proj)
// block 384 (6 waves); per thread 4o x 4px.
__global__ __launch_bounds__(384) void k_out(
    const float* __restrict__ vbuf, const float* __restrict__ w2,
    float* __restrict__ out)
{
  __shared__ __align__(16) float Al[16 * 196];   // [k][o] pad 196
  __shared__ __align__(16) float Bl[16 * 32];
  int blk = blockIdx.x;
  int b = blk / 288;
  int pix0 = (blk % 288) * 32;
  int t = threadIdx.x;
  int og = t >> 3, pg = t & 7;                   // og 0..47 -> o = og*4+i
  float acc[4][4] = {};
  float ra[8], rb2[2];
#pragma unroll
  for (int i = 0; i < 8; ++i) {
    int e = t + i * 384;
    ra[i] = w2[(size_t)(b * 192 + (e >> 4)) * 192 + (e & 15)];
  }
#pragma unroll
  for (int i = 0; i < 2; ++i) {
    int e = t + i * 384;
    rb2[i] = (e < 512) ? vbuf[(size_t)(b * 192 + (e >> 5)) * 9216 + pix0 + (e & 31)] : 0.f;
  }
  for (int c0 = 0; c0 < 192; c0 += 16) {
#pragma unroll
    for (int i = 0; i < 8; ++i) {
      int e = t + i * 384;
      Al[(e & 15) * 196 + (e >> 4)] = ra[i];
    }
#pragma unroll
    for (int i = 0; i < 2; ++i) {
      int e = t + i * 384;
      if (e < 512) Bl[e] = rb2[i];
    }
    __syncthreads();
    if (c0 + 16 < 192) {
#pragma unroll
      for (int i = 0; i < 8; ++i) {
        int e = t + i * 384;
        ra[i] = w2[(size_t)(b * 192 + (e >> 4)) * 192 + c0 + 16 + (e & 15)];
      }
#pragma unroll
      for (int i = 0; i < 2; ++i) {
        int e = t + i * 384;
        rb2[i] = (e < 512) ? vbuf[(size_t)(b * 192 + c0 + 16 + (e >> 5)) * 9216 + pix0 + (e & 31)] : 0.f;
      }
    }
    const float4* B4 = (const float4*)Bl;
    const float4* A4 = (const float4*)Al;
#pragma unroll
    for (int k = 0; k < 16; ++k) {
      float4 bv = B4[k * 8 + pg];
      float4 a0 = A4[k * 49 + og];
      float av[4] = {a0.x, a0.y, a0.z, a0.w};
#pragma unroll
      for (int i = 0; i < 4; ++i) {
        acc[i][0] += av[i] * bv.x; acc[i][1] += av[i] * bv.y;
        acc[i][2] += av[i] * bv.z; acc[i][3] += av[i] * bv.w;
      }
    }
    __syncthreads();
  }
#pragma unroll
  for (int i = 0; i < 4; ++i) {
    int o = og * 4 + i;
    *(float4*)&out[(size_t)(b * 192 + o) * 9216 + pix0 + pg * 4]
        = {acc[i][0], acc[i][1], acc[i][2], acc[i][3]};
  }
}

// ----------------------------------------------------------------
extern "C" void kernel_launch(void* const* d_in, const int* in_sizes, int n_in,
                              void* d_out, int out_size, void* d_ws, size_t ws_size,
                              hipStream_t stream) {
  (void)in_sizes; (void)n_in; (void)out_size; (void)ws_size;
  const float* x     = (const float*)d_in[0];
  const float* pw    = (const float*)d_in[1];
  const float* pb    = (const float*)d_in[2];
  const float* dw    = (const float*)d_in[3];
  const float* qkvw  = (const float*)d_in[4];
  const float* projw = (const float*)d_in[5];
  const float* temp  = (const float*)d_in[6];
  float* ws   = (float*)d_ws;
  float* off  = ws + OFF_OFS;
  float* qb   = ws + Q_OFS;
  float* kb   = ws + K_OFS;
  float* vb   = ws + V_OFS;
  float* nq   = ws + NQ_OFS;
  float* nk   = ws + NK_OFS;
  float* part = ws + PART_OFS;
  float* attn = ws + ATTN_OFS;
  float* w2   = ws + W2_OFS;
  float* out  = (float*)d_out;

  k_zero       <<<dim3(3456), dim3(256), 0, stream>>>((float4*)qb, 884736);
  k_offset_conv<<<dim3(216),  dim3(192), 0, stream>>>(x, pw, pb, off);
  k_qkv        <<<dim3(576),  dim3(384), 0, stream>>>(x, qkvw, kb, vb);
  k_deform     <<<dim3(1152), dim3(192), 0, stream>>>(x, off, dw, qb);
  k_norms      <<<dim3(768),  dim3(256), 0, stream>>>(qb, kb, nq, nk);
  k_gram       <<<dim3(288),  dim3(256), 0, stream>>>(qb, kb, part);
  k_softmax    <<<dim3(12),   dim3(1024),0, stream>>>(part, nq, nk, temp, attn);
  k_w2         <<<dim3(12),   dim3(256), 0, stream>>>(attn, projw, w2);
  k_out        <<<dim3(576),  dim3(384), 0, stream>>>(vb, w2, out);
}

// Round 5
// 1086.527 us; speedup vs baseline: 1.1283x; 1.0503x over previous
//
#include <hip/hip_runtime.h>

// MSDformer: deformable conv (q) + transposed-channel attention + proj.
// R5: deform path restructured: k_sample materializes im2col B (bf16,
// [pix][k] rows) -> k_dgemm does q = W x B via bf16 MFMA, zero LDS/barriers.
// q only affects the output through softmax weights -> bf16-safe.
constexpr int SPLITS = 24;
constexpr size_t OFF_OFS  = 0;                         // [2][18][9216] f32
constexpr size_t Q_OFS    = 331776;                    // [2][192][9216] f32
constexpr size_t K_OFS    = Q_OFS + 3538944;
constexpr size_t V_OFS    = K_OFS + 3538944;
constexpr size_t NQ_OFS   = V_OFS + 3538944;           // [2*192] inv-norms
constexpr size_t NK_OFS   = NQ_OFS + 384;
constexpr size_t PART_OFS = NK_OFS + 384;              // [24][12][1024]
constexpr size_t ATTN_OFS = PART_OFS + (size_t)SPLITS * 12 * 1024;  // [12][1024]
constexpr size_t W2_OFS   = ATTN_OFS + 12288;          // [2][192][192]
constexpr size_t XOFF_OFS = 11330304;                  // [9216][1728] bf16 (one batch)
constexpr size_t WBT_OFS  = XOFF_OFS + 7962624;        // [192][1728] bf16
// total ws: 19,458,816 floats = 77.8 MB

typedef __attribute__((ext_vector_type(8))) short bf16x8;
typedef __attribute__((ext_vector_type(4))) float f32x4;

__device__ __forceinline__ unsigned bf16rne(float f) {
  unsigned u = __float_as_uint(f);
  return (u + 0x7fffu + ((u >> 16) & 1u)) >> 16;
}

// ---------------------------------------------------------------- K1: offset conv (unchanged)
__global__ __launch_bounds__(192) void k_offset_conv(
    const float* __restrict__ x, const float* __restrict__ pw,
    const float* __restrict__ pb, float* __restrict__ off)
{
  __shared__ __align__(16) float sx[4 * 10 * 100];
  int blk = blockIdx.x;
  int b  = blk / 108;
  int r  = blk % 108;
  int o0 = (r / 12) * 2;
  int h0 = (r % 12) * 8;
  int t  = threadIdx.x;
  int prow = (4 * t) / 96;
  int wb   = (4 * t) % 96;
  float acc[2][4] = {};
  for (int c0 = 0; c0 < 192; c0 += 4) {
    __syncthreads();
    for (int e = t; e < 3920; e += 192) {
      int ch = e / 980, r2 = e % 980;
      int row = r2 / 98, col = r2 % 98;
      int gr = h0 + row - 1, gc = col - 1;
      float v = 0.f;
      if (gr >= 0 && gr < 96 && gc >= 0 && gc < 96)
        v = x[((b * 192 + c0 + ch) * 96 + gr) * 96 + gc];
      sx[ch * 1000 + row * 100 + col] = v;
    }
    __syncthreads();
#pragma unroll
    for (int ch = 0; ch < 4; ++ch) {
      float w0[9], w1[9];
#pragma unroll
      for (int kk = 0; kk < 9; ++kk) {
        w0[kk] = pw[(o0 * 192 + c0 + ch) * 9 + kk];
        w1[kk] = pw[((o0 + 1) * 192 + c0 + ch) * 9 + kk];
      }
#pragma unroll
      for (int ki = 0; ki < 3; ++ki) {
        const float* base = &sx[ch * 1000 + (prow + ki) * 100 + wb];
        float4 f4 = *(const float4*)base;
        float2 f2 = *(const float2*)(base + 4);
        float xv[6] = {f4.x, f4.y, f4.z, f4.w, f2.x, f2.y};
#pragma unroll
        for (int kj = 0; kj < 3; ++kj)
#pragma unroll
          for (int p = 0; p < 4; ++p) {
            acc[0][p] += w0[ki * 3 + kj] * xv[kj + p];
            acc[1][p] += w1[ki * 3 + kj] * xv[kj + p];
          }
      }
    }
  }
  float bb0 = pb[o0], bb1 = pb[o0 + 1];
  int orow = h0 + prow;
  float4 s0 = {acc[0][0] + bb0, acc[0][1] + bb0, acc[0][2] + bb0, acc[0][3] + bb0};
  float4 s1 = {acc[1][0] + bb1, acc[1][1] + bb1, acc[1][2] + bb1, acc[1][3] + bb1};
  *(float4*)&off[((b * 18 + o0) * 96 + orow) * 96 + wb] = s0;
  *(float4*)&off[((b * 18 + o0 + 1) * 96 + orow) * 96 + wb] = s1;
}

// ---------------------------------------------------------------- K2a: dw fp32 -> bf16
__global__ __launch_bounds__(256) void k_cvtw(
    const float4* __restrict__ dw4, uint2* __restrict__ out, int n4)
{
  int i = blockIdx.x * 256 + threadIdx.x;
  if (i < n4) {
    float4 v = dw4[i];
    out[i] = uint2{bf16rne(v.x) | (bf16rne(v.y) << 16),
                   bf16rne(v.z) | (bf16rne(v.w) << 16)};
  }
}

// ---------------------------------------------------------------- K2b: bilinear sample -> xofft[pix][k] bf16
__device__ __forceinline__ float deform_slow_sample(
    const float* __restrict__ x, const float* __restrict__ off,
    int b, int c, int n, int h, int w)
{
  int ki = n / 3, kj = n % 3;
  float ox = off[((b * 18 + n) * 96 + h) * 96 + w];
  float oy = off[((b * 18 + 9 + n) * 96 + h) * 96 + w];
  float px = (float)(h + ki) + ox;
  float py = (float)(w + kj) + oy;
  float fx = floorf(px), fy = floorf(py);
  int qx0 = max(0, min(97, (int)fx));
  int qx1 = max(0, min(97, (int)fx + 1));
  int qy0 = max(0, min(97, (int)fy));
  int qy1 = max(0, min(97, (int)fy + 1));
  float pxc = fminf(fmaxf(px, 0.f), 97.f);
  float pyc = fminf(fmaxf(py, 0.f), 97.f);
  float wx0 = 1.f + ((float)qx0 - pxc);
  float wx1 = 1.f - ((float)qx1 - pxc);
  float wy0 = 1.f + ((float)qy0 - pyc);
  float wy1 = 1.f - ((float)qy1 - pyc);
  auto xp = [&](int qx, int qy) -> float {
    int X = qx - 1, Y = qy - 1;
    return (X >= 0 && X < 96 && Y >= 0 && Y < 96)
               ? x[((b * 192 + c) * 96 + X) * 96 + Y] : 0.f;
  };
  return wx0 * wy0 * xp(qx0, qy0) + wx1 * wy1 * xp(qx1, qy1)
       + wx0 * wy1 * xp(qx0, qy1) + wx1 * wy0 * xp(qx1, qy0);
}

constexpr int SCH = 24;                      // channels per chunk
__global__ __launch_bounds__(192) void k_sample(
    const float* __restrict__ x, const float* __restrict__ off,
    unsigned* __restrict__ xoffu, int b)
{
  __shared__ __align__(16) float4 tg[288];   // bilinear weights (lt,rb,lb,rt)
  __shared__ unsigned tq[288];               // packed band-local idx + flag
  __shared__ int sbb[572];                   // band src addr (c=0), -1 = outside
  __shared__ float band[SCH * 572];          // x band [cc][13*44]
  int blk = blockIdx.x;
  int h  = blk / 3;
  int w0 = (blk % 3) * 32;
  int t  = threadIdx.x;

  for (int e = t; e < 288; e += 192) {
    int n = e >> 5, pix = e & 31;
    int ki = n / 3, kj = n % 3;
    int w = w0 + pix;
    float ox = off[((b * 18 + n) * 96 + h) * 96 + w];
    float oy = off[((b * 18 + 9 + n) * 96 + h) * 96 + w];
    float px = (float)(h + ki) + ox;
    float py = (float)(w + kj) + oy;
    float fx = floorf(px), fy = floorf(py);
    int qx0 = max(0, min(97, (int)fx));
    int qx1 = max(0, min(97, (int)fx + 1));
    int qy0 = max(0, min(97, (int)fy));
    int qy1 = max(0, min(97, (int)fy + 1));
    float pxc = fminf(fmaxf(px, 0.f), 97.f);
    float pyc = fminf(fmaxf(py, 0.f), 97.f);
    float wx0 = 1.f + ((float)qx0 - pxc);
    float wx1 = 1.f - ((float)qx1 - pxc);
    float wy0 = 1.f + ((float)qy0 - pyc);
    float wy1 = 1.f - ((float)qy1 - pyc);
    float4 g = {wx0 * wy0, wx1 * wy1, wx0 * wy1, wx1 * wy0};
    int lx0 = qx0 - h + 5, lx1 = qx1 - h + 5;
    int ly0 = qy0 - w0 + 5, ly1 = qy1 - w0 + 5;
    unsigned flag = (lx0 >= 0 && lx1 < 13 && ly0 >= 0 && ly1 < 44) ? 1u : 0u;
    lx0 = max(0, min(12, lx0)); lx1 = max(0, min(12, lx1));
    ly0 = max(0, min(43, ly0)); ly1 = max(0, min(43, ly1));
    tg[e] = g;
    tq[e] = (unsigned)lx0 | ((unsigned)ly0 << 5) | ((unsigned)lx1 << 11)
          | ((unsigned)ly1 << 16) | (flag << 31);
  }
  for (int e = t; e < 572; e += 192) {
    int lx = e / 44, ly = e % 44;
    int X = h - 6 + lx, Y = w0 - 6 + ly;
    sbb[e] = (X >= 0 && X < 96 && Y >= 0 && Y < 96)
                 ? ((b * 192) * 96 + X) * 96 + Y : -1;
  }
  __syncthreads();

  int px = t & 31, cg = t >> 5;              // 6 groups x 4 channels
  for (int c0 = 0; c0 < 192; c0 += SCH) {
    for (int i = 0; i < (SCH * 572 + 191) / 192; ++i) {
      int e = t + i * 192;
      if (e < SCH * 572) {
        int cc = e / 572, r2 = e % 572;
        int sb = sbb[r2];
        band[e] = (sb >= 0) ? x[sb + (c0 + cc) * 9216] : 0.f;
      }
    }
    __syncthreads();
    float vv[36];
#pragma unroll
    for (int i = 0; i < 4; ++i) {
      int cc = cg * 4 + i;
#pragma unroll
      for (int n = 0; n < 9; ++n) {
        int e2 = n * 32 + px;
        float4 g = tg[e2];
        unsigned u = tq[e2];
        float val;
        if (u >> 31) {
          int lx0 = u & 31, ly0 = (u >> 5) & 63, lx1 = (u >> 11) & 31, ly1 = (u >> 16) & 63;
          const float* bd = &band[cc * 572];
          val = g.x * bd[lx0 * 44 + ly0] + g.y * bd[lx1 * 44 + ly1]
              + g.z * bd[lx0 * 44 + ly1] + g.w * bd[lx1 * 44 + ly0];
        } else {
          val = deform_slow_sample(x, off, b, c0 + cc, n, h, w0 + px);
        }
        vv[i * 9 + n] = val;
      }
    }
    unsigned baseDW = ((unsigned)(h * 96 + w0 + px) * 1728u
                     + (unsigned)(c0 + cg * 4) * 9u) >> 1;
#pragma unroll
    for (int jj = 0; jj < 18; ++jj)
      xoffu[baseDW + jj] = bf16rne(vv[2 * jj]) | (bf16rne(vv[2 * jj + 1]) << 16);
    __syncthreads();
  }
}

// ---------------------------------------------------------------- K2c: q = W(bf16) @ xofft(bf16), MFMA, no LDS
// grid 1152 = 288 pixtiles(32) x 4 otiles(48); block 64 (1 wave).
// Wave tile 48o x 32px = 3x2 mfma_16x16x32 frags; operands straight from L2.
__global__ __launch_bounds__(64) void k_dgemm(
    const unsigned short* __restrict__ xofft, const unsigned short* __restrict__ wbt,
    float* __restrict__ q, int b)
{
  int blk = blockIdx.x;
  int og = blk & 3;
  int pt = blk >> 2;
  int l  = threadIdx.x;
  int lo = l & 15, hi = l >> 4;
  const char* X = (const char*)xofft;
  const char* W = (const char*)wbt;
  size_t a0 = ((size_t)(og * 48 + lo)      * 1728 + hi * 8) * 2;
  size_t a1 = ((size_t)(og * 48 + 16 + lo) * 1728 + hi * 8) * 2;
  size_t a2 = ((size_t)(og * 48 + 32 + lo) * 1728 + hi * 8) * 2;
  size_t b0 = ((size_t)(pt * 32 + lo)      * 1728 + hi * 8) * 2;
  size_t b1 = ((size_t)(pt * 32 + 16 + lo) * 1728 + hi * 8) * 2;
  f32x4 acc00 = {}, acc01 = {}, acc10 = {}, acc11 = {}, acc20 = {}, acc21 = {};
#pragma unroll 2
  for (int k0 = 0; k0 < 3456; k0 += 64) {    // byte step = 32 k * 2B
    bf16x8 av0 = *(const bf16x8*)(W + a0 + k0);
    bf16x8 av1 = *(const bf16x8*)(W + a1 + k0);
    bf16x8 av2 = *(const bf16x8*)(W + a2 + k0);
    bf16x8 bv0 = *(const bf16x8*)(X + b0 + k0);
    bf16x8 bv1 = *(const bf16x8*)(X + b1 + k0);
    acc00 = __builtin_amdgcn_mfma_f32_16x16x32_bf16(av0, bv0, acc00, 0, 0, 0);
    acc01 = __builtin_amdgcn_mfma_f32_16x16x32_bf16(av0, bv1, acc01, 0, 0, 0);
    acc10 = __builtin_amdgcn_mfma_f32_16x16x32_bf16(av1, bv0, acc10, 0, 0, 0);
    acc11 = __builtin_amdgcn_mfma_f32_16x16x32_bf16(av1, bv1, acc11, 0, 0, 0);
    acc20 = __builtin_amdgcn_mfma_f32_16x16x32_bf16(av2, bv0, acc20, 0, 0, 0);
    acc21 = __builtin_amdgcn_mfma_f32_16x16x32_bf16(av2, bv1, acc21, 0, 0, 0);
  }
  // D: col(lane&15)=px, row((lane>>4)*4+r)=o within frag -> coalesced stores
  f32x4* accs[3][2] = {{&acc00, &acc01}, {&acc10, &acc11}, {&acc20, &acc21}};
#pragma unroll
  for (int fo = 0; fo < 3; ++fo)
#pragma unroll
    for (int fp = 0; fp < 2; ++fp)
#pragma unroll
      for (int r = 0; r < 4; ++r)
        q[(size_t)(b * 192 + og * 48 + fo * 16 + hi * 4 + r) * 9216
          + pt * 32 + fp * 16 + lo] = (*accs[fo][fp])[r];
}

// ---------------------------------------------------------------- K3: k,v GEMM (unchanged)
__global__ __launch_bounds__(384) void k_qkv(
    const float* __restrict__ x, const float* __restrict__ qkvw,
    float* __restrict__ kbuf, float* __restrict__ vbuf)
{
  __shared__ __align__(16) float Al[16 * 388];
  __shared__ __align__(16) float Bl[16 * 32];
  int blk = blockIdx.x;
  int b = blk / 288;
  int pix0 = (blk % 288) * 32;
  int t = threadIdx.x;
  int og = t >> 3, pg = t & 7;
  float acc[8][4] = {};
  float ra[16], rb2[2];
#pragma unroll
  for (int i = 0; i < 16; ++i) {
    int e = t + i * 384;
    ra[i] = qkvw[(size_t)(192 + (e >> 4)) * 192 + (e & 15)];
  }
#pragma unroll
  for (int i = 0; i < 2; ++i) {
    int e = t + i * 384;
    rb2[i] = (e < 512) ? x[(size_t)(b * 192 + (e >> 5)) * 9216 + pix0 + (e & 31)] : 0.f;
  }
  for (int c0 = 0; c0 < 192; c0 += 16) {
#pragma unroll
    for (int i = 0; i < 16; ++i) {
      int e = t + i * 384;
      Al[(e & 15) * 388 + (e >> 4)] = ra[i];
    }
#pragma unroll
    for (int i = 0; i < 2; ++i) {
      int e = t + i * 384;
      if (e < 512) Bl[e] = rb2[i];
    }
    __syncthreads();
    if (c0 + 16 < 192) {
#pragma unroll
      for (int i = 0; i < 16; ++i) {
        int e = t + i * 384;
        ra[i] = qkvw[(size_t)(192 + (e >> 4)) * 192 + c0 + 16 + (e & 15)];
      }
#pragma unroll
      for (int i = 0; i < 2; ++i) {
        int e = t + i * 384;
        rb2[i] = (e < 512) ? x[(size_t)(b * 192 + c0 + 16 + (e >> 5)) * 9216 + pix0 + (e & 31)] : 0.f;
      }
    }
    const float4* B4 = (const float4*)Bl;
    const float4* A4 = (const float4*)Al;
#pragma unroll
    for (int k = 0; k < 16; ++k) {
      float4 bv = B4[k * 8 + pg];
      float4 va0 = A4[k * 97 + og * 2];
      float4 va1 = A4[k * 97 + og * 2 + 1];
      float av[8] = {va0.x, va0.y, va0.z, va0.w, va1.x, va1.y, va1.z, va1.w};
#pragma unroll
      for (int i = 0; i < 8; ++i) {
        acc[i][0] += av[i] * bv.x; acc[i][1] += av[i] * bv.y;
        acc[i][2] += av[i] * bv.z; acc[i][3] += av[i] * bv.w;
      }
    }
    __syncthreads();
  }
#pragma unroll
  for (int i = 0; i < 8; ++i) {
    int o = og * 8 + i;
    float* dst = (o < 192) ? &kbuf[(size_t)(b * 192 + o) * 9216]
                           : &vbuf[(size_t)(b * 192 + o - 192) * 9216];
    *(float4*)(dst + pix0 + pg * 4) = {acc[i][0], acc[i][1], acc[i][2], acc[i][3]};
  }
}

// ---------------------------------------------------------------- K4: inv L2 norms (unchanged)
__global__ __launch_bounds__(256) void k_norms(
    const float* __restrict__ qbuf, const float* __restrict__ kbuf,
    float* __restrict__ nq, float* __restrict__ nk)
{
  __shared__ float red[4];
  int blk = blockIdx.x;
  int which = blk / 384, r = blk % 384;
  const float* src = (which ? kbuf : qbuf) + (size_t)r * 9216;
  int t = threadIdx.x;
  float s = 0.f;
  const float4* s4 = (const float4*)src;
  for (int i = t; i < 2304; i += 256) {
    float4 v = s4[i];
    s += v.x * v.x + v.y * v.y + v.z * v.z + v.w * v.w;
  }
#pragma unroll
  for (int o = 32; o; o >>= 1) s += __shfl_xor(s, o);
  if ((t & 63) == 0) red[t >> 6] = s;
  __syncthreads();
  if (t == 0) {
    float tot = red[0] + red[1] + red[2] + red[3];
    (which ? nk : nq)[r] = 1.f / fmaxf(sqrtf(tot), 1e-12f);
  }
}

// ---------------------------------------------------------------- K5: Gram partials (unchanged)
__global__ __launch_bounds__(256) void k_gram(
    const float* __restrict__ qbuf, const float* __restrict__ kbuf,
    float* __restrict__ part)
{
  __shared__ float sq[32 * 65], sk[32 * 65];
  int blk = blockIdx.x;
  int split = blk / 12, r = blk % 12;
  int b = r / 6, hh = r % 6;
  int n0 = split * 384;
  int t = threadIdx.x;
  int c = t >> 3, dg = t & 7;
  float acc[4] = {};
  for (int sc = 0; sc < 6; ++sc) {
    __syncthreads();
    for (int i = t; i < 2048; i += 256) {
      int cc = i >> 6, j = i & 63;
      size_t g = (size_t)(b * 192 + hh * 32 + cc) * 9216 + n0 + sc * 64 + j;
      sq[cc * 65 + j] = qbuf[g];
      sk[cc * 65 + j] = kbuf[g];
    }
    __syncthreads();
#pragma unroll 8
    for (int j = 0; j < 64; ++j) {
      float qv = sq[c * 65 + j];
#pragma unroll
      for (int i2 = 0; i2 < 4; ++i2)
        acc[i2] += qv * sk[(dg * 4 + i2) * 65 + j];
    }
  }
  float* dst = &part[((size_t)split * 12 + b * 6 + hh) * 1024 + c * 32 + dg * 4];
  *(float4*)dst = {acc[0], acc[1], acc[2], acc[3]};
}

// ---------------------------------------------------------------- K6: softmax (unchanged)
__global__ __launch_bounds__(1024) void k_softmax(
    const float* __restrict__ part, const float* __restrict__ nq,
    const float* __restrict__ nk, const float* __restrict__ temp,
    float* __restrict__ attn)
{
  int bi = blockIdx.x;
  int b = bi / 6, h = bi % 6;
  int t = threadIdx.x;
  int c = t >> 5, d = t & 31;
  float val = 0.f;
  for (int s = 0; s < SPLITS; ++s) val += part[((size_t)s * 12 + bi) * 1024 + t];
  val *= nq[b * 192 + h * 32 + c] * nk[b * 192 + h * 32 + d] * temp[h];
  float m = val;
#pragma unroll
  for (int o = 16; o; o >>= 1) m = fmaxf(m, __shfl_xor(m, o));
  float e = expf(val - m);
  float s = e;
#pragma unroll
  for (int o = 16; o; o >>= 1) s += __shfl_xor(s, o);
  attn[(size_t)bi * 1024 + t] = e / s;
}

// ---------------------------------------------------------------- K7: W2 = proj . blockdiag(attn) (unchanged)
__global__ __launch_bounds__(256) void k_w2(
    const float* __restrict__ attn, const float* __restrict__ projw,
    float* __restrict__ w2)
{
  __shared__ float sa[32 * 33];
  int bi = blockIdx.x;
  int b = bi / 6, h = bi % 6;
  int t = threadIdx.x;
  for (int i = t; i < 1024; i += 256)
    sa[(i >> 5) * 33 + (i & 31)] = attn[(size_t)bi * 1024 + i];
  __syncthreads();
  for (int e = t; e < 6144; e += 256) {
    int o = e >> 5, d = e & 31;
    float s = 0.f;
#pragma unroll 8
    for (int ci = 0; ci < 32; ++ci)
      s += projw[o * 192 + h * 32 + ci] * sa[ci * 33 + d];
    w2[((size_t)b * 192 + o) * 192 + h * 32 + d] = s;
  }
}

// ---------------------------------------------------------------- K8: out = W2 @ v (unchanged)
__global__ __launch_bounds__(384) void k_out(
    const float* __restrict__ vbuf, const float* __restrict__ w2,
    float* __restrict__ out)
{
  __shared__ __align__(16) float Al[16 * 196];
  __shared__ __align__(16) float Bl[16 * 32];
  int blk = blockIdx.x;
  int b = blk / 288;
  int pix0 = (blk % 288) * 32;
  int t = threadIdx.x;
  int og = t >> 3, pg = t & 7;
  float acc[4][4] = {};
  float ra[8], rb2[2];
#pragma unroll
  for (int i = 0; i < 8; ++i) {
    int e = t + i * 384;
    ra[i] = w2[(size_t)(b * 192 + (e >> 4)) * 192 + (e & 15)];
  }
#pragma unroll
  for (int i = 0; i < 2; ++i) {
    int e = t + i * 384;
    rb2[i] = (e < 512) ? vbuf[(size_t)(b * 192 + (e >> 5)) * 9216 + pix0 + (e & 31)] : 0.f;
  }
  for (int c0 = 0; c0 < 192; c0 += 16) {
#pragma unroll
    for (int i = 0; i < 8; ++i) {
      int e = t + i * 384;
      Al[(e & 15) * 196 + (e >> 4)] = ra[i];
    }
#pragma unroll
    for (int i = 0; i < 2; ++i) {
      int e = t + i * 384;
      if (e < 512) Bl[e] = rb2[i];
    }
    __syncthreads();
    if (c0 + 16 < 192) {
#pragma unroll
      for (int i = 0; i < 8; ++i) {
        int e = t + i * 384;
        ra[i] = w2[(size_t)(b * 192 + (e >> 4)) * 192 + c0 + 16 + (e & 15)];
      }
#pragma unroll
      for (int i = 0; i < 2; ++i) {
        int e = t + i * 384;
        rb2[i] = (e < 512) ? vbuf[(size_t)(b * 192 + c0 + 16 + (e >> 5)) * 9216 + pix0 + (e & 31)] : 0.f;
      }
    }
    const float4* B4 = (const float4*)Bl;
    const float4* A4 = (const float4*)Al;
#pragma unroll
    for (int k = 0; k < 16; ++k) {
      float4 bv = B4[k * 8 + pg];
      float4 va = A4[k * 49 + og];
      float av[4] = {va.x, va.y, va.z, va.w};
#pragma unroll
      for (int i = 0; i < 4; ++i) {
        acc[i][0] += av[i] * bv.x; acc[i][1] += av[i] * bv.y;
        acc[i][2] += av[i] * bv.z; acc[i][3] += av[i] * bv.w;
      }
    }
    __syncthreads();
  }
#pragma unroll
  for (int i = 0; i < 4; ++i) {
    int o = og * 4 + i;
    *(float4*)&out[(size_t)(b * 192 + o) * 9216 + pix0 + pg * 4]
        = {acc[i][0], acc[i][1], acc[i][2], acc[i][3]};
  }
}

// ----------------------------------------------------------------
extern "C" void kernel_launch(void* const* d_in, const int* in_sizes, int n_in,
                              void* d_out, int out_size, void* d_ws, size_t ws_size,
                              hipStream_t stream) {
  (void)in_sizes; (void)n_in; (void)out_size; (void)ws_size;
  const float* x     = (const float*)d_in[0];
  const float* pw    = (const float*)d_in[1];
  const float* pb    = (const float*)d_in[2];
  const float* dw    = (const float*)d_in[3];
  const float* qkvw  = (const float*)d_in[4];
  const float* projw = (const float*)d_in[5];
  const float* temp  = (const float*)d_in[6];
  float* ws   = (float*)d_ws;
  float* off  = ws + OFF_OFS;
  float* qb   = ws + Q_OFS;
  float* kb   = ws + K_OFS;
  float* vb   = ws + V_OFS;
  float* nq   = ws + NQ_OFS;
  float* nk   = ws + NK_OFS;
  float* part = ws + PART_OFS;
  float* attn = ws + ATTN_OFS;
  float* w2   = ws + W2_OFS;
  unsigned*       xoffu = (unsigned*)(ws + XOFF_OFS);
  unsigned short* xofft = (unsigned short*)xoffu;
  unsigned short* wbt   = (unsigned short*)(ws + WBT_OFS);
  float* out  = (float*)d_out;

  k_offset_conv<<<dim3(216), dim3(192), 0, stream>>>(x, pw, pb, off);
  k_cvtw       <<<dim3(324), dim3(256), 0, stream>>>((const float4*)dw, (uint2*)wbt, 82944);
  k_qkv        <<<dim3(576), dim3(384), 0, stream>>>(x, qkvw, kb, vb);
  for (int b = 0; b < 2; ++b) {
    k_sample   <<<dim3(288),  dim3(192), 0, stream>>>(x, off, xoffu, b);
    k_dgemm    <<<dim3(1152), dim3(64),  0, stream>>>(xofft, wbt, qb, b);
  }
  k_norms      <<<dim3(768), dim3(256), 0, stream>>>(qb, kb, nq, nk);
  k_gram       <<<dim3(288), dim3(256), 0, stream>>>(qb, kb, part);
  k_softmax    <<<dim3(12),  dim3(1024),0, stream>>>(part, nq, nk, temp, attn);
  k_w2         <<<dim3(12),  dim3(256), 0, stream>>>(attn, projw, w2);
  k_out        <<<dim3(576), dim3(384), 0, stream>>>(vb, w2, out);
}

// Round 6
// 584.691 us; speedup vs baseline: 2.0968x; 1.8583x over previous
//
#include <hip/hip_runtime.h>

// MSDformer: deformable conv (q) + transposed-channel attention + proj.
// R6: offset conv c-split 12 ways (part into XOFF scratch + reduce w/ bias) to
// fix 0.84 blocks/CU grid starvation; k_sample c-split 4 ways (1.1->4.5 blk/CU).
constexpr int SPLITS = 24;
constexpr size_t OFF_OFS  = 0;                         // [2][18][9216] f32
constexpr size_t Q_OFS    = 331776;                    // [2][192][9216] f32
constexpr size_t K_OFS    = Q_OFS + 3538944;
constexpr size_t V_OFS    = K_OFS + 3538944;
constexpr size_t NQ_OFS   = V_OFS + 3538944;           // [2*192] inv-norms
constexpr size_t NK_OFS   = NQ_OFS + 384;
constexpr size_t PART_OFS = NK_OFS + 384;              // [24][12][1024]
constexpr size_t ATTN_OFS = PART_OFS + (size_t)SPLITS * 12 * 1024;  // [12][1024]
constexpr size_t W2_OFS   = ATTN_OFS + 12288;          // [2][192][192]
constexpr size_t XOFF_OFS = 11330304;                  // [9216][1728] bf16 == offc partials [12][663552] f32
constexpr size_t WBT_OFS  = XOFF_OFS + 7962624;        // [192][1728] bf16
// total ws: 19,458,816 floats = 77.8 MB

typedef __attribute__((ext_vector_type(8))) short bf16x8;
typedef __attribute__((ext_vector_type(4))) float f32x4;

__device__ __forceinline__ unsigned bf16rne(float f) {
  unsigned u = __float_as_uint(f);
  return (u + 0x7fffu + ((u >> 16) & 1u)) >> 16;
}

// ---------------------------------------------------------------- K1a: offset conv partials
// grid 1152 = 12 csplit x B x 48 rowpairs; block 192 = 2 rows x 96 px.
// Thread owns 1 pixel x all 18 o; 16 channels per block; weights via s_load.
__global__ __launch_bounds__(192) void k_offc_part(
    const float* __restrict__ x, const float* __restrict__ pw,
    float* __restrict__ part)
{
  __shared__ float band[16 * 4 * 98];          // [cc][row 4][col 98]
  int blk = blockIdx.x;
  int csp = blk % 12;
  int rem = blk / 12;
  int b  = rem / 48;
  int r0 = (rem % 48) * 2;
  int c0 = csp * 16;
  int t  = threadIdx.x;
  int r = t / 96, w = t % 96;

  // stage 16 channels x rows r0-1..r0+2 x cols -1..96 (zero-padded)
  for (int i = 0; i < 33; ++i) {
    int e = t + i * 192;
    if (e < 6272) {
      int cc = e / 392, r2 = e % 392;
      int row = r2 / 98, col = r2 % 98;
      int gr = r0 + row - 1, gc = col - 1;
      float v = 0.f;
      if (gr >= 0 && gr < 96 && gc >= 0 && gc < 96)
        v = x[((b * 192 + c0 + cc) * 96 + gr) * 96 + gc];
      band[cc * 392 + row * 98 + col] = v;
    }
  }
  __syncthreads();

  float acc[18] = {};
#pragma unroll 4
  for (int cc = 0; cc < 16; ++cc) {
    float bv[9];
#pragma unroll
    for (int ki = 0; ki < 3; ++ki)
#pragma unroll
      for (int kj = 0; kj < 3; ++kj)
        bv[ki * 3 + kj] = band[cc * 392 + (r + ki) * 98 + w + kj];
#pragma unroll
    for (int o = 0; o < 18; ++o) {
      float w9[9];
#pragma unroll
      for (int kk = 0; kk < 9; ++kk)        // wave-uniform -> s_load
        w9[kk] = pw[(o * 192 + c0 + cc) * 9 + kk];
#pragma unroll
      for (int kk = 0; kk < 9; ++kk)
        acc[o] += w9[kk] * bv[kk];
    }
  }
  float* dst = &part[(size_t)csp * 663552 + ((size_t)(b * 18) * 96 + r0 + r) * 96 + w];
#pragma unroll
  for (int o = 0; o < 18; ++o)
    dst[(size_t)o * 9216] = acc[o];
}

// ---------------------------------------------------------------- K1b: reduce partials + bias
__global__ __launch_bounds__(256) void k_offc_red(
    const float4* __restrict__ part4, const float* __restrict__ pb,
    float4* __restrict__ off4)
{
  int i4 = blockIdx.x * 256 + threadIdx.x;
  if (i4 >= 165888) return;
  int o = ((i4 * 4) / 9216) % 18;
  float bb = pb[o];
  float4 s = {bb, bb, bb, bb};
  for (int sp = 0; sp < 12; ++sp) {
    float4 v = part4[(size_t)sp * 165888 + i4];
    s.x += v.x; s.y += v.y; s.z += v.z; s.w += v.w;
  }
  off4[i4] = s;
}

// ---------------------------------------------------------------- K2a: dw fp32 -> bf16
__global__ __launch_bounds__(256) void k_cvtw(
    const float4* __restrict__ dw4, uint2* __restrict__ out, int n4)
{
  int i = blockIdx.x * 256 + threadIdx.x;
  if (i < n4) {
    float4 v = dw4[i];
    out[i] = uint2{bf16rne(v.x) | (bf16rne(v.y) << 16),
                   bf16rne(v.z) | (bf16rne(v.w) << 16)};
  }
}

// ---------------------------------------------------------------- K2b: bilinear sample -> xofft[pix][k] bf16
__device__ __forceinline__ float deform_slow_sample(
    const float* __restrict__ x, const float* __restrict__ off,
    int b, int c, int n, int h, int w)
{
  int ki = n / 3, kj = n % 3;
  float ox = off[((b * 18 + n) * 96 + h) * 96 + w];
  float oy = off[((b * 18 + 9 + n) * 96 + h) * 96 + w];
  float px = (float)(h + ki) + ox;
  float py = (float)(w + kj) + oy;
  float fx = floorf(px), fy = floorf(py);
  int qx0 = max(0, min(97, (int)fx));
  int qx1 = max(0, min(97, (int)fx + 1));
  int qy0 = max(0, min(97, (int)fy));
  int qy1 = max(0, min(97, (int)fy + 1));
  float pxc = fminf(fmaxf(px, 0.f), 97.f);
  float pyc = fminf(fmaxf(py, 0.f), 97.f);
  float wx0 = 1.f + ((float)qx0 - pxc);
  float wx1 = 1.f - ((float)qx1 - pxc);
  float wy0 = 1.f + ((float)qy0 - pyc);
  float wy1 = 1.f - ((float)qy1 - pyc);
  auto xp = [&](int qx, int qy) -> float {
    int X = qx - 1, Y = qy - 1;
    return (X >= 0 && X < 96 && Y >= 0 && Y < 96)
               ? x[((b * 192 + c) * 96 + X) * 96 + Y] : 0.f;
  };
  return wx0 * wy0 * xp(qx0, qy0) + wx1 * wy1 * xp(qx1, qy1)
       + wx0 * wy1 * xp(qx0, qy1) + wx1 * wy0 * xp(qx1, qy0);
}

constexpr int SCH = 12;                      // channels per chunk
__global__ __launch_bounds__(192) void k_sample(
    const float* __restrict__ x, const float* __restrict__ off,
    unsigned* __restrict__ xoffu, int b)
{
  __shared__ __align__(16) float4 tg[288];   // bilinear weights (lt,rb,lb,rt)
  __shared__ unsigned tq[288];               // packed band-local idx + flag
  __shared__ int sbb[572];                   // band src addr (c=0), -1 = outside
  __shared__ float band[SCH * 572];          // x band [cc][13*44]
  int blk = blockIdx.x;                      // 1152 = 288 tiles x 4 csplit
  int csp = blk & 3;
  int tile = blk >> 2;
  int h  = tile / 3;
  int w0 = (tile % 3) * 32;
  int t  = threadIdx.x;

  for (int e = t; e < 288; e += 192) {
    int n = e >> 5, pix = e & 31;
    int ki = n / 3, kj = n % 3;
    int w = w0 + pix;
    float ox = off[((b * 18 + n) * 96 + h) * 96 + w];
    float oy = off[((b * 18 + 9 + n) * 96 + h) * 96 + w];
    float px = (float)(h + ki) + ox;
    float py = (float)(w + kj) + oy;
    float fx = floorf(px), fy = floorf(py);
    int qx0 = max(0, min(97, (int)fx));
    int qx1 = max(0, min(97, (int)fx + 1));
    int qy0 = max(0, min(97, (int)fy));
    int qy1 = max(0, min(97, (int)fy + 1));
    float pxc = fminf(fmaxf(px, 0.f), 97.f);
    float pyc = fminf(fmaxf(py, 0.f), 97.f);
    float wx0 = 1.f + ((float)qx0 - pxc);
    float wx1 = 1.f - ((float)qx1 - pxc);
    float wy0 = 1.f + ((float)qy0 - pyc);
    float wy1 = 1.f - ((float)qy1 - pyc);
    float4 g = {wx0 * wy0, wx1 * wy1, wx0 * wy1, wx1 * wy0};
    int lx0 = qx0 - h + 5, lx1 = qx1 - h + 5;
    int ly0 = qy0 - w0 + 5, ly1 = qy1 - w0 + 5;
    unsigned flag = (lx0 >= 0 && lx1 < 13 && ly0 >= 0 && ly1 < 44) ? 1u : 0u;
    lx0 = max(0, min(12, lx0)); lx1 = max(0, min(12, lx1));
    ly0 = max(0, min(43, ly0)); ly1 = max(0, min(43, ly1));
    tg[e] = g;
    tq[e] = (unsigned)lx0 | ((unsigned)ly0 << 5) | ((unsigned)lx1 << 11)
          | ((unsigned)ly1 << 16) | (flag << 31);
  }
  for (int e = t; e < 572; e += 192) {
    int lx = e / 44, ly = e % 44;
    int X = h - 6 + lx, Y = w0 - 6 + ly;
    sbb[e] = (X >= 0 && X < 96 && Y >= 0 && Y < 96)
                 ? ((b * 192) * 96 + X) * 96 + Y : -1;
  }
  __syncthreads();

  int px = t & 31, cg = t >> 5;              // 6 groups x 2 channels
  for (int c0 = csp * 48; c0 < csp * 48 + 48; c0 += SCH) {
    for (int i = 0; i < (SCH * 572 + 191) / 192; ++i) {
      int e = t + i * 192;
      if (e < SCH * 572) {
        int cc = e / 572, r2 = e % 572;
        int sb = sbb[r2];
        band[e] = (sb >= 0) ? x[sb + (c0 + cc) * 9216] : 0.f;
      }
    }
    __syncthreads();
    float vv[18];
#pragma unroll
    for (int i = 0; i < 2; ++i) {
      int cc = cg * 2 + i;
#pragma unroll
      for (int n = 0; n < 9; ++n) {
        int e2 = n * 32 + px;
        float4 g = tg[e2];
        unsigned u = tq[e2];
        float val;
        if (u >> 31) {
          int lx0 = u & 31, ly0 = (u >> 5) & 63, lx1 = (u >> 11) & 31, ly1 = (u >> 16) & 63;
          const float* bd = &band[cc * 572];
          val = g.x * bd[lx0 * 44 + ly0] + g.y * bd[lx1 * 44 + ly1]
              + g.z * bd[lx0 * 44 + ly1] + g.w * bd[lx1 * 44 + ly0];
        } else {
          val = deform_slow_sample(x, off, b, c0 + cc, n, h, w0 + px);
        }
        vv[i * 9 + n] = val;
      }
    }
    unsigned baseDW = ((unsigned)(h * 96 + w0 + px) * 1728u
                     + (unsigned)(c0 + cg * 2) * 9u) >> 1;
#pragma unroll
    for (int jj = 0; jj < 9; ++jj)
      xoffu[baseDW + jj] = bf16rne(vv[2 * jj]) | (bf16rne(vv[2 * jj + 1]) << 16);
    __syncthreads();
  }
}

// ---------------------------------------------------------------- K2c: q = W(bf16) @ xofft(bf16), MFMA, no LDS
// grid 1152 = 288 pixtiles(32) x 4 otiles(48); block 64 (1 wave).
__global__ __launch_bounds__(64) void k_dgemm(
    const unsigned short* __restrict__ xofft, const unsigned short* __restrict__ wbt,
    float* __restrict__ q, int b)
{
  int blk = blockIdx.x;
  int og = blk & 3;
  int pt = blk >> 2;
  int l  = threadIdx.x;
  int lo = l & 15, hi = l >> 4;
  const char* X = (const char*)xofft;
  const char* W = (const char*)wbt;
  size_t a0 = ((size_t)(og * 48 + lo)      * 1728 + hi * 8) * 2;
  size_t a1 = ((size_t)(og * 48 + 16 + lo) * 1728 + hi * 8) * 2;
  size_t a2 = ((size_t)(og * 48 + 32 + lo) * 1728 + hi * 8) * 2;
  size_t b0 = ((size_t)(pt * 32 + lo)      * 1728 + hi * 8) * 2;
  size_t b1 = ((size_t)(pt * 32 + 16 + lo) * 1728 + hi * 8) * 2;
  f32x4 acc00 = {}, acc01 = {}, acc10 = {}, acc11 = {}, acc20 = {}, acc21 = {};
#pragma unroll 2
  for (int k0 = 0; k0 < 3456; k0 += 64) {    // byte step = 32 k * 2B
    bf16x8 av0 = *(const bf16x8*)(W + a0 + k0);
    bf16x8 av1 = *(const bf16x8*)(W + a1 + k0);
    bf16x8 av2 = *(const bf16x8*)(W + a2 + k0);
    bf16x8 bv0 = *(const bf16x8*)(X + b0 + k0);
    bf16x8 bv1 = *(const bf16x8*)(X + b1 + k0);
    acc00 = __builtin_amdgcn_mfma_f32_16x16x32_bf16(av0, bv0, acc00, 0, 0, 0);
    acc01 = __builtin_amdgcn_mfma_f32_16x16x32_bf16(av0, bv1, acc01, 0, 0, 0);
    acc10 = __builtin_amdgcn_mfma_f32_16x16x32_bf16(av1, bv0, acc10, 0, 0, 0);
    acc11 = __builtin_amdgcn_mfma_f32_16x16x32_bf16(av1, bv1, acc11, 0, 0, 0);
    acc20 = __builtin_amdgcn_mfma_f32_16x16x32_bf16(av2, bv0, acc20, 0, 0, 0);
    acc21 = __builtin_amdgcn_mfma_f32_16x16x32_bf16(av2, bv1, acc21, 0, 0, 0);
  }
  f32x4* accs[3][2] = {{&acc00, &acc01}, {&acc10, &acc11}, {&acc20, &acc21}};
#pragma unroll
  for (int fo = 0; fo < 3; ++fo)
#pragma unroll
    for (int fp = 0; fp < 2; ++fp)
#pragma unroll
      for (int r = 0; r < 4; ++r)
        q[(size_t)(b * 192 + og * 48 + fo * 16 + hi * 4 + r) * 9216
          + pt * 32 + fp * 16 + lo] = (*accs[fo][fp])[r];
}

// ---------------------------------------------------------------- K3: k,v GEMM (unchanged)
__global__ __launch_bounds__(384) void k_qkv(
    const float* __restrict__ x, const float* __restrict__ qkvw,
    float* __restrict__ kbuf, float* __restrict__ vbuf)
{
  __shared__ __align__(16) float Al[16 * 388];
  __shared__ __align__(16) float Bl[16 * 32];
  int blk = blockIdx.x;
  int b = blk / 288;
  int pix0 = (blk % 288) * 32;
  int t = threadIdx.x;
  int og = t >> 3, pg = t & 7;
  float acc[8][4] = {};
  float ra[16], rb2[2];
#pragma unroll
  for (int i = 0; i < 16; ++i) {
    int e = t + i * 384;
    ra[i] = qkvw[(size_t)(192 + (e >> 4)) * 192 + (e & 15)];
  }
#pragma unroll
  for (int i = 0; i < 2; ++i) {
    int e = t + i * 384;
    rb2[i] = (e < 512) ? x[(size_t)(b * 192 + (e >> 5)) * 9216 + pix0 + (e & 31)] : 0.f;
  }
  for (int c0 = 0; c0 < 192; c0 += 16) {
#pragma unroll
    for (int i = 0; i < 16; ++i) {
      int e = t + i * 384;
      Al[(e & 15) * 388 + (e >> 4)] = ra[i];
    }
#pragma unroll
    for (int i = 0; i < 2; ++i) {
      int e = t + i * 384;
      if (e < 512) Bl[e] = rb2[i];
    }
    __syncthreads();
    if (c0 + 16 < 192) {
#pragma unroll
      for (int i = 0; i < 16; ++i) {
        int e = t + i * 384;
        ra[i] = qkvw[(size_t)(192 + (e >> 4)) * 192 + c0 + 16 + (e & 15)];
      }
#pragma unroll
      for (int i = 0; i < 2; ++i) {
        int e = t + i * 384;
        rb2[i] = (e < 512) ? x[(size_t)(b * 192 + c0 + 16 + (e >> 5)) * 9216 + pix0 + (e & 31)] : 0.f;
      }
    }
    const float4* B4 = (const float4*)Bl;
    const float4* A4 = (const float4*)Al;
#pragma unroll
    for (int k = 0; k < 16; ++k) {
      float4 bv = B4[k * 8 + pg];
      float4 va0 = A4[k * 97 + og * 2];
      float4 va1 = A4[k * 97 + og * 2 + 1];
      float av[8] = {va0.x, va0.y, va0.z, va0.w, va1.x, va1.y, va1.z, va1.w};
#pragma unroll
      for (int i = 0; i < 8; ++i) {
        acc[i][0] += av[i] * bv.x; acc[i][1] += av[i] * bv.y;
        acc[i][2] += av[i] * bv.z; acc[i][3] += av[i] * bv.w;
      }
    }
    __syncthreads();
  }
#pragma unroll
  for (int i = 0; i < 8; ++i) {
    int o = og * 8 + i;
    float* dst = (o < 192) ? &kbuf[(size_t)(b * 192 + o) * 9216]
                           : &vbuf[(size_t)(b * 192 + o - 192) * 9216];
    *(float4*)(dst + pix0 + pg * 4) = {acc[i][0], acc[i][1], acc[i][2], acc[i][3]};
  }
}

// ---------------------------------------------------------------- K4: inv L2 norms (unchanged)
__global__ __launch_bounds__(256) void k_norms(
    const float* __restrict__ qbuf, const float* __restrict__ kbuf,
    float* __restrict__ nq, float* __restrict__ nk)
{
  __shared__ float red[4];
  int blk = blockIdx.x;
  int which = blk / 384, r = blk % 384;
  const float* src = (which ? kbuf : qbuf) + (size_t)r * 9216;
  int t = threadIdx.x;
  float s = 0.f;
  const float4* s4 = (const float4*)src;
  for (int i = t; i < 2304; i += 256) {
    float4 v = s4[i];
    s += v.x * v.x + v.y * v.y + v.z * v.z + v.w * v.w;
  }
#pragma unroll
  for (int o = 32; o; o >>= 1) s += __shfl_xor(s, o);
  if ((t & 63) == 0) red[t >> 6] = s;
  __syncthreads();
  if (t == 0) {
    float tot = red[0] + red[1] + red[2] + red[3];
    (which ? nk : nq)[r] = 1.f / fmaxf(sqrtf(tot), 1e-12f);
  }
}

// ---------------------------------------------------------------- K5: Gram partials (unchanged)
__global__ __launch_bounds__(256) void k_gram(
    const float* __restrict__ qbuf, const float* __restrict__ kbuf,
    float* __restrict__ part)
{
  __shared__ float sq[32 * 65], sk[32 * 65];
  int blk = blockIdx.x;
  int split = blk / 12, r = blk % 12;
  int b = r / 6, hh = r % 6;
  int n0 = split * 384;
  int t = threadIdx.x;
  int c = t >> 3, dg = t & 7;
  float acc[4] = {};
  for (int sc = 0; sc < 6; ++sc) {
    __syncthreads();
    for (int i = t; i < 2048; i += 256) {
      int cc = i >> 6, j = i & 63;
      size_t g = (size_t)(b * 192 + hh * 32 + cc) * 9216 + n0 + sc * 64 + j;
      sq[cc * 65 + j] = qbuf[g];
      sk[cc * 65 + j] = kbuf[g];
    }
    __syncthreads();
#pragma unroll 8
    for (int j = 0; j < 64; ++j) {
      float qv = sq[c * 65 + j];
#pragma unroll
      for (int i2 = 0; i2 < 4; ++i2)
        acc[i2] += qv * sk[(dg * 4 + i2) * 65 + j];
    }
  }
  float* dst = &part[((size_t)split * 12 + b * 6 + hh) * 1024 + c * 32 + dg * 4];
  *(float4*)dst = {acc[0], acc[1], acc[2], acc[3]};
}

// ---------------------------------------------------------------- K6: softmax (unchanged)
__global__ __launch_bounds__(1024) void k_softmax(
    const float* __restrict__ part, const float* __restrict__ nq,
    const float* __restrict__ nk, const float* __restrict__ temp,
    float* __restrict__ attn)
{
  int bi = blockIdx.x;
  int b = bi / 6, h = bi % 6;
  int t = threadIdx.x;
  int c = t >> 5, d = t & 31;
  float val = 0.f;
  for (int s = 0; s < SPLITS; ++s) val += part[((size_t)s * 12 + bi) * 1024 + t];
  val *= nq[b * 192 + h * 32 + c] * nk[b * 192 + h * 32 + d] * temp[h];
  float m = val;
#pragma unroll
  for (int o = 16; o; o >>= 1) m = fmaxf(m, __shfl_xor(m, o));
  float e = expf(val - m);
  float s = e;
#pragma unroll
  for (int o = 16; o; o >>= 1) s += __shfl_xor(s, o);
  attn[(size_t)bi * 1024 + t] = e / s;
}

// ---------------------------------------------------------------- K7: W2 = proj . blockdiag(attn) (unchanged)
__global__ __launch_bounds__(256) void k_w2(
    const float* __restrict__ attn, const float* __restrict__ projw,
    float* __restrict__ w2)
{
  __shared__ float sa[32 * 33];
  int bi = blockIdx.x;
  int b = bi / 6, h = bi % 6;
  int t = threadIdx.x;
  for (int i = t; i < 1024; i += 256)
    sa[(i >> 5) * 33 + (i & 31)] = attn[(size_t)bi * 1024 + i];
  __syncthreads();
  for (int e = t; e < 6144; e += 256) {
    int o = e >> 5, d = e & 31;
    float s = 0.f;
#pragma unroll 8
    for (int ci = 0; ci < 32; ++ci)
      s += projw[o * 192 + h * 32 + ci] * sa[ci * 33 + d];
    w2[((size_t)b * 192 + o) * 192 + h * 32 + d] = s;
  }
}

// ---------------------------------------------------------------- K8: out = W2 @ v (unchanged)
__global__ __launch_bounds__(384) void k_out(
    const float* __restrict__ vbuf, const float* __restrict__ w2,
    float* __restrict__ out)
{
  __shared__ __align__(16) float Al[16 * 196];
  __shared__ __align__(16) float Bl[16 * 32];
  int blk = blockIdx.x;
  int b = blk / 288;
  int pix0 = (blk % 288) * 32;
  int t = threadIdx.x;
  int og = t >> 3, pg = t & 7;
  float acc[4][4] = {};
  float ra[8], rb2[2];
#pragma unroll
  for (int i = 0; i < 8; ++i) {
    int e = t + i * 384;
    ra[i] = w2[(size_t)(b * 192 + (e >> 4)) * 192 + (e & 15)];
  }
#pragma unroll
  for (int i = 0; i < 2; ++i) {
    int e = t + i * 384;
    rb2[i] = (e < 512) ? vbuf[(size_t)(b * 192 + (e >> 5)) * 9216 + pix0 + (e & 31)] : 0.f;
  }
  for (int c0 = 0; c0 < 192; c0 += 16) {
#pragma unroll
    for (int i = 0; i < 8; ++i) {
      int e = t + i * 384;
      Al[(e & 15) * 196 + (e >> 4)] = ra[i];
    }
#pragma unroll
    for (int i = 0; i < 2; ++i) {
      int e = t + i * 384;
      if (e < 512) Bl[e] = rb2[i];
    }
    __syncthreads();
    if (c0 + 16 < 192) {
#pragma unroll
      for (int i = 0; i < 8; ++i) {
        int e = t + i * 384;
        ra[i] = w2[(size_t)(b * 192 + (e >> 4)) * 192 + c0 + 16 + (e & 15)];
      }
#pragma unroll
      for (int i = 0; i < 2; ++i) {
        int e = t + i * 384;
        rb2[i] = (e < 512) ? vbuf[(size_t)(b * 192 + c0 + 16 + (e >> 5)) * 9216 + pix0 + (e & 31)] : 0.f;
      }
    }
    const float4* B4 = (const float4*)Bl;
    const float4* A4 = (const float4*)Al;
#pragma unroll
    for (int k = 0; k < 16; ++k) {
      float4 bv = B4[k * 8 + pg];
      float4 va = A4[k * 49 + og];
      float av[4] = {va.x, va.y, va.z, va.w};
#pragma unroll
      for (int i = 0; i < 4; ++i) {
        acc[i][0] += av[i] * bv.x; acc[i][1] += av[i] * bv.y;
        acc[i][2] += av[i] * bv.z; acc[i][3] += av[i] * bv.w;
      }
    }
    __syncthreads();
  }
#pragma unroll
  for (int i = 0; i < 4; ++i) {
    int o = og * 4 + i;
    *(float4*)&out[(size_t)(b * 192 + o) * 9216 + pix0 + pg * 4]
        = {acc[i][0], acc[i][1], acc[i][2], acc[i][3]};
  }
}

// ----------------------------------------------------------------
extern "C" void kernel_launch(void* const* d_in, const int* in_sizes, int n_in,
                              void* d_out, int out_size, void* d_ws, size_t ws_size,
                              hipStream_t stream) {
  (void)in_sizes; (void)n_in; (void)out_size; (void)ws_size;
  const float* x     = (const float*)d_in[0];
  const float* pw    = (const float*)d_in[1];
  const float* pb    = (const float*)d_in[2];
  const float* dw    = (const float*)d_in[3];
  const float* qkvw  = (const float*)d_in[4];
  const float* projw = (const float*)d_in[5];
  const float* temp  = (const float*)d_in[6];
  float* ws   = (float*)d_ws;
  float* off  = ws + OFF_OFS;
  float* qb   = ws + Q_OFS;
  float* kb   = ws + K_OFS;
  float* vb   = ws + V_OFS;
  float* nq   = ws + NQ_OFS;
  float* nk   = ws + NK_OFS;
  float* part = ws + PART_OFS;
  float* attn = ws + ATTN_OFS;
  float* w2   = ws + W2_OFS;
  float* opart = ws + XOFF_OFS;                 // offc partials, then xofft
  unsigned*       xoffu = (unsigned*)(ws + XOFF_OFS);
  unsigned short* xofft = (unsigned short*)xoffu;
  unsigned short* wbt   = (unsigned short*)(ws + WBT_OFS);
  float* out  = (float*)d_out;

  k_offc_part  <<<dim3(1152), dim3(192), 0, stream>>>(x, pw, opart);
  k_offc_red   <<<dim3(648),  dim3(256), 0, stream>>>((const float4*)opart, pb, (float4*)off);
  k_cvtw       <<<dim3(324),  dim3(256), 0, stream>>>((const float4*)dw, (uint2*)wbt, 82944);
  k_qkv        <<<dim3(576),  dim3(384), 0, stream>>>(x, qkvw, kb, vb);
  for (int b = 0; b < 2; ++b) {
    k_sample   <<<dim3(1152), dim3(192), 0, stream>>>(x, off, xoffu, b);
    k_dgemm    <<<dim3(1152), dim3(64),  0, stream>>>(xofft, wbt, qb, b);
  }
  k_norms      <<<dim3(768),  dim3(256), 0, stream>>>(qb, kb, nq, nk);
  k_gram       <<<dim3(288),  dim3(256), 0, stream>>>(qb, kb, part);
  k_softmax    <<<dim3(12),   dim3(1024),0, stream>>>(part, nq, nk, temp, attn);
  k_w2         <<<dim3(12),   dim3(256), 0, stream>>>(attn, projw, w2);
  k_out        <<<dim3(576),  dim3(384), 0, stream>>>(vb, w2, out);
}

// Round 7
// 481.976 us; speedup vs baseline: 2.5436x; 1.2131x over previous
//
#include <hip/hip_runtime.h>

// MSDformer: deformable conv (q) + transposed-channel attention + proj.
// R7: k_sample rebuilt as direct-gather (no band staging/slow path): LDS SoA
// tables of {4 weights (0 for OOB), 4 clamped abs offsets} per (n,pix);
// gathers hit L1/L2 (x is L3-resident). 1 barrier, 9.2 KB LDS.
constexpr int SPLITS = 24;
constexpr size_t OFF_OFS  = 0;                         // [2][18][9216] f32
constexpr size_t Q_OFS    = 331776;                    // [2][192][9216] f32
constexpr size_t K_OFS    = Q_OFS + 3538944;
constexpr size_t V_OFS    = K_OFS + 3538944;
constexpr size_t NQ_OFS   = V_OFS + 3538944;           // [2*192] inv-norms
constexpr size_t NK_OFS   = NQ_OFS + 384;
constexpr size_t PART_OFS = NK_OFS + 384;              // [24][12][1024]
constexpr size_t ATTN_OFS = PART_OFS + (size_t)SPLITS * 12 * 1024;  // [12][1024]
constexpr size_t W2_OFS   = ATTN_OFS + 12288;          // [2][192][192]
constexpr size_t XOFF_OFS = 11330304;                  // [9216][1728] bf16 == offc partials [12][663552] f32
constexpr size_t WBT_OFS  = XOFF_OFS + 7962624;        // [192][1728] bf16
// total ws: 19,458,816 floats = 77.8 MB

typedef __attribute__((ext_vector_type(8))) short bf16x8;
typedef __attribute__((ext_vector_type(4))) float f32x4;

__device__ __forceinline__ unsigned bf16rne(float f) {
  unsigned u = __float_as_uint(f);
  return (u + 0x7fffu + ((u >> 16) & 1u)) >> 16;
}

// ---------------------------------------------------------------- K1a: offset conv partials
// grid 1152 = 12 csplit x B x 48 rowpairs; block 192 = 2 rows x 96 px.
__global__ __launch_bounds__(192) void k_offc_part(
    const float* __restrict__ x, const float* __restrict__ pw,
    float* __restrict__ part)
{
  __shared__ float band[16 * 4 * 98];          // [cc][row 4][col 98]
  int blk = blockIdx.x;
  int csp = blk % 12;
  int rem = blk / 12;
  int b  = rem / 48;
  int r0 = (rem % 48) * 2;
  int c0 = csp * 16;
  int t  = threadIdx.x;
  int r = t / 96, w = t % 96;

  for (int i = 0; i < 33; ++i) {
    int e = t + i * 192;
    if (e < 6272) {
      int cc = e / 392, r2 = e % 392;
      int row = r2 / 98, col = r2 % 98;
      int gr = r0 + row - 1, gc = col - 1;
      float v = 0.f;
      if (gr >= 0 && gr < 96 && gc >= 0 && gc < 96)
        v = x[((b * 192 + c0 + cc) * 96 + gr) * 96 + gc];
      band[cc * 392 + row * 98 + col] = v;
    }
  }
  __syncthreads();

  float acc[18] = {};
#pragma unroll 4
  for (int cc = 0; cc < 16; ++cc) {
    float bv[9];
#pragma unroll
    for (int ki = 0; ki < 3; ++ki)
#pragma unroll
      for (int kj = 0; kj < 3; ++kj)
        bv[ki * 3 + kj] = band[cc * 392 + (r + ki) * 98 + w + kj];
#pragma unroll
    for (int o = 0; o < 18; ++o) {
      float w9[9];
#pragma unroll
      for (int kk = 0; kk < 9; ++kk)        // wave-uniform -> s_load
        w9[kk] = pw[(o * 192 + c0 + cc) * 9 + kk];
#pragma unroll
      for (int kk = 0; kk < 9; ++kk)
        acc[o] += w9[kk] * bv[kk];
    }
  }
  float* dst = &part[(size_t)csp * 663552 + ((size_t)(b * 18) * 96 + r0 + r) * 96 + w];
#pragma unroll
  for (int o = 0; o < 18; ++o)
    dst[(size_t)o * 9216] = acc[o];
}

// ---------------------------------------------------------------- K1b: reduce partials + bias
__global__ __launch_bounds__(256) void k_offc_red(
    const float4* __restrict__ part4, const float* __restrict__ pb,
    float4* __restrict__ off4)
{
  int i4 = blockIdx.x * 256 + threadIdx.x;
  if (i4 >= 165888) return;
  int o = ((i4 * 4) / 9216) % 18;
  float bb = pb[o];
  float4 s = {bb, bb, bb, bb};
  for (int sp = 0; sp < 12; ++sp) {
    float4 v = part4[(size_t)sp * 165888 + i4];
    s.x += v.x; s.y += v.y; s.z += v.z; s.w += v.w;
  }
  off4[i4] = s;
}

// ---------------------------------------------------------------- K2a: dw fp32 -> bf16
__global__ __launch_bounds__(256) void k_cvtw(
    const float4* __restrict__ dw4, uint2* __restrict__ out, int n4)
{
  int i = blockIdx.x * 256 + threadIdx.x;
  if (i < n4) {
    float4 v = dw4[i];
    out[i] = uint2{bf16rne(v.x) | (bf16rne(v.y) << 16),
                   bf16rne(v.z) | (bf16rne(v.w) << 16)};
  }
}

// ---------------------------------------------------------------- K2b: direct-gather sample -> xofft[pix][k] bf16
// grid 1152 = 288 tiles x 4 csplit(48ch); block 256 = 32 px x 8 cg x 6 ch.
// LDS SoA tables: weight=0 for corners outside image (== zero-padded x),
// offsets clamped -> handles any offset magnitude, no slow path.
__global__ __launch_bounds__(256) void k_sample(
    const float* __restrict__ x, const float* __restrict__ off,
    unsigned* __restrict__ xoffu, int b)
{
  __shared__ float twt[4][288];
  __shared__ int   tof[4][288];
  int blk = blockIdx.x;
  int csp = blk & 3;
  int tile = blk >> 2;
  int h  = tile / 3;
  int w0 = (tile % 3) * 32;
  int t  = threadIdx.x;

  for (int e = t; e < 288; e += 256) {
    int n = e >> 5, pix = e & 31;
    int ki = n / 3, kj = n % 3;
    int w = w0 + pix;
    float ox = off[((b * 18 + n) * 96 + h) * 96 + w];
    float oy = off[((b * 18 + 9 + n) * 96 + h) * 96 + w];
    float px = (float)(h + ki) + ox;
    float py = (float)(w + kj) + oy;
    float fx = floorf(px), fy = floorf(py);
    int qx0 = max(0, min(97, (int)fx));
    int qx1 = max(0, min(97, (int)fx + 1));
    int qy0 = max(0, min(97, (int)fy));
    int qy1 = max(0, min(97, (int)fy + 1));
    float pxc = fminf(fmaxf(px, 0.f), 97.f);
    float pyc = fminf(fmaxf(py, 0.f), 97.f);
    float wx0 = 1.f + ((float)qx0 - pxc);
    float wx1 = 1.f - ((float)qx1 - pxc);
    float wy0 = 1.f + ((float)qy0 - pyc);
    float wy1 = 1.f - ((float)qy1 - pyc);
    int X0 = qx0 - 1, X1 = qx1 - 1, Y0 = qy0 - 1, Y1 = qy1 - 1;
    bool vX0 = (unsigned)X0 < 96u, vX1 = (unsigned)X1 < 96u;
    bool vY0 = (unsigned)Y0 < 96u, vY1 = (unsigned)Y1 < 96u;
    twt[0][e] = (vX0 && vY0) ? wx0 * wy0 : 0.f;   // lt -> (qx0,qy0)
    tof[0][e] = (vX0 && vY0) ? X0 * 96 + Y0 : 0;
    twt[1][e] = (vX1 && vY1) ? wx1 * wy1 : 0.f;   // rb -> (qx1,qy1)
    tof[1][e] = (vX1 && vY1) ? X1 * 96 + Y1 : 0;
    twt[2][e] = (vX0 && vY1) ? wx0 * wy1 : 0.f;   // lb -> (qx0,qy1)
    tof[2][e] = (vX0 && vY1) ? X0 * 96 + Y1 : 0;
    twt[3][e] = (vX1 && vY0) ? wx1 * wy0 : 0.f;   // rt -> (qx1,qy0)
    tof[3][e] = (vX1 && vY0) ? X1 * 96 + Y0 : 0;
  }
  __syncthreads();

  int px = t & 31, cg = t >> 5;
  int c0 = csp * 48 + cg * 6;
  const float* bas = x + (size_t)(b * 192 + c0) * 9216;
  unsigned pixg = (unsigned)(h * 96 + w0 + px);
  for (int cp = 0; cp < 3; ++cp) {
    float vv[2][9];
#pragma unroll
    for (int n = 0; n < 9; ++n) {
      int e2 = n * 32 + px;
      float wlt = twt[0][e2], wrb = twt[1][e2], wlb = twt[2][e2], wrt = twt[3][e2];
      int olt = tof[0][e2], orb = tof[1][e2], olb = tof[2][e2], ort = tof[3][e2];
      const float* b0 = bas + cp * 2 * 9216;
      const float* b1 = b0 + 9216;
      vv[0][n] = wlt * b0[olt] + wrb * b0[orb] + wlb * b0[olb] + wrt * b0[ort];
      vv[1][n] = wlt * b1[olt] + wrb * b1[orb] + wlb * b1[olb] + wrt * b1[ort];
    }
    unsigned baseDW = (pixg * 1728u + (unsigned)(c0 + cp * 2) * 9u) >> 1;
#pragma unroll
    for (int jj = 0; jj < 9; ++jj) {
      constexpr int idx0[9] = {0,0,0,0,0,1,1,1,1};   // (2jj)/9
      constexpr int idx1[9] = {0,0,0,0,1,1,1,1,1};   // (2jj+1)/9
      xoffu[baseDW + jj] = bf16rne(vv[idx0[jj]][(2 * jj) % 9])
                         | (bf16rne(vv[idx1[jj]][(2 * jj + 1) % 9]) << 16);
    }
  }
}

// ---------------------------------------------------------------- K2c: q = W(bf16) @ xofft(bf16), MFMA, no LDS
// grid 1152 = 288 pixtiles(32) x 4 otiles(48); block 64 (1 wave).
__global__ __launch_bounds__(64) void k_dgemm(
    const unsigned short* __restrict__ xofft, const unsigned short* __restrict__ wbt,
    float* __restrict__ q, int b)
{
  int blk = blockIdx.x;
  int og = blk & 3;
  int pt = blk >> 2;
  int l  = threadIdx.x;
  int lo = l & 15, hi = l >> 4;
  const char* X = (const char*)xofft;
  const char* W = (const char*)wbt;
  size_t a0 = ((size_t)(og * 48 + lo)      * 1728 + hi * 8) * 2;
  size_t a1 = ((size_t)(og * 48 + 16 + lo) * 1728 + hi * 8) * 2;
  size_t a2 = ((size_t)(og * 48 + 32 + lo) * 1728 + hi * 8) * 2;
  size_t b0 = ((size_t)(pt * 32 + lo)      * 1728 + hi * 8) * 2;
  size_t b1 = ((size_t)(pt * 32 + 16 + lo) * 1728 + hi * 8) * 2;
  f32x4 acc00 = {}, acc01 = {}, acc10 = {}, acc11 = {}, acc20 = {}, acc21 = {};
#pragma unroll 2
  for (int k0 = 0; k0 < 3456; k0 += 64) {    // byte step = 32 k * 2B
    bf16x8 av0 = *(const bf16x8*)(W + a0 + k0);
    bf16x8 av1 = *(const bf16x8*)(W + a1 + k0);
    bf16x8 av2 = *(const bf16x8*)(W + a2 + k0);
    bf16x8 bv0 = *(const bf16x8*)(X + b0 + k0);
    bf16x8 bv1 = *(const bf16x8*)(X + b1 + k0);
    acc00 = __builtin_amdgcn_mfma_f32_16x16x32_bf16(av0, bv0, acc00, 0, 0, 0);
    acc01 = __builtin_amdgcn_mfma_f32_16x16x32_bf16(av0, bv1, acc01, 0, 0, 0);
    acc10 = __builtin_amdgcn_mfma_f32_16x16x32_bf16(av1, bv0, acc10, 0, 0, 0);
    acc11 = __builtin_amdgcn_mfma_f32_16x16x32_bf16(av1, bv1, acc11, 0, 0, 0);
    acc20 = __builtin_amdgcn_mfma_f32_16x16x32_bf16(av2, bv0, acc20, 0, 0, 0);
    acc21 = __builtin_amdgcn_mfma_f32_16x16x32_bf16(av2, bv1, acc21, 0, 0, 0);
  }
  f32x4* accs[3][2] = {{&acc00, &acc01}, {&acc10, &acc11}, {&acc20, &acc21}};
#pragma unroll
  for (int fo = 0; fo < 3; ++fo)
#pragma unroll
    for (int fp = 0; fp < 2; ++fp)
#pragma unroll
      for (int r = 0; r < 4; ++r)
        q[(size_t)(b * 192 + og * 48 + fo * 16 + hi * 4 + r) * 9216
          + pt * 32 + fp * 16 + lo] = (*accs[fo][fp])[r];
}

// ---------------------------------------------------------------- K3: k,v GEMM (unchanged)
__global__ __launch_bounds__(384) void k_qkv(
    const float* __restrict__ x, const float* __restrict__ qkvw,
    float* __restrict__ kbuf, float* __restrict__ vbuf)
{
  __shared__ __align__(16) float Al[16 * 388];
  __shared__ __align__(16) float Bl[16 * 32];
  int blk = blockIdx.x;
  int b = blk / 288;
  int pix0 = (blk % 288) * 32;
  int t = threadIdx.x;
  int og = t >> 3, pg = t & 7;
  float acc[8][4] = {};
  float ra[16], rb2[2];
#pragma unroll
  for (int i = 0; i < 16; ++i) {
    int e = t + i * 384;
    ra[i] = qkvw[(size_t)(192 + (e >> 4)) * 192 + (e & 15)];
  }
#pragma unroll
  for (int i = 0; i < 2; ++i) {
    int e = t + i * 384;
    rb2[i] = (e < 512) ? x[(size_t)(b * 192 + (e >> 5)) * 9216 + pix0 + (e & 31)] : 0.f;
  }
  for (int c0 = 0; c0 < 192; c0 += 16) {
#pragma unroll
    for (int i = 0; i < 16; ++i) {
      int e = t + i * 384;
      Al[(e & 15) * 388 + (e >> 4)] = ra[i];
    }
#pragma unroll
    for (int i = 0; i < 2; ++i) {
      int e = t + i * 384;
      if (e < 512) Bl[e] = rb2[i];
    }
    __syncthreads();
    if (c0 + 16 < 192) {
#pragma unroll
      for (int i = 0; i < 16; ++i) {
        int e = t + i * 384;
        ra[i] = qkvw[(size_t)(192 + (e >> 4)) * 192 + c0 + 16 + (e & 15)];
      }
#pragma unroll
      for (int i = 0; i < 2; ++i) {
        int e = t + i * 384;
        rb2[i] = (e < 512) ? x[(size_t)(b * 192 + c0 + 16 + (e >> 5)) * 9216 + pix0 + (e & 31)] : 0.f;
      }
    }
    const float4* B4 = (const float4*)Bl;
    const float4* A4 = (const float4*)Al;
#pragma unroll
    for (int k = 0; k < 16; ++k) {
      float4 bv = B4[k * 8 + pg];
      float4 va0 = A4[k * 97 + og * 2];
      float4 va1 = A4[k * 97 + og * 2 + 1];
      float av[8] = {va0.x, va0.y, va0.z, va0.w, va1.x, va1.y, va1.z, va1.w};
#pragma unroll
      for (int i = 0; i < 8; ++i) {
        acc[i][0] += av[i] * bv.x; acc[i][1] += av[i] * bv.y;
        acc[i][2] += av[i] * bv.z; acc[i][3] += av[i] * bv.w;
      }
    }
    __syncthreads();
  }
#pragma unroll
  for (int i = 0; i < 8; ++i) {
    int o = og * 8 + i;
    float* dst = (o < 192) ? &kbuf[(size_t)(b * 192 + o) * 9216]
                           : &vbuf[(size_t)(b * 192 + o - 192) * 9216];
    *(float4*)(dst + pix0 + pg * 4) = {acc[i][0], acc[i][1], acc[i][2], acc[i][3]};
  }
}

// ---------------------------------------------------------------- K4: inv L2 norms (unchanged)
__global__ __launch_bounds__(256) void k_norms(
    const float* __restrict__ qbuf, const float* __restrict__ kbuf,
    float* __restrict__ nq, float* __restrict__ nk)
{
  __shared__ float red[4];
  int blk = blockIdx.x;
  int which = blk / 384, r = blk % 384;
  const float* src = (which ? kbuf : qbuf) + (size_t)r * 9216;
  int t = threadIdx.x;
  float s = 0.f;
  const float4* s4 = (const float4*)src;
  for (int i = t; i < 2304; i += 256) {
    float4 v = s4[i];
    s += v.x * v.x + v.y * v.y + v.z * v.z + v.w * v.w;
  }
#pragma unroll
  for (int o = 32; o; o >>= 1) s += __shfl_xor(s, o);
  if ((t & 63) == 0) red[t >> 6] = s;
  __syncthreads();
  if (t == 0) {
    float tot = red[0] + red[1] + red[2] + red[3];
    (which ? nk : nq)[r] = 1.f / fmaxf(sqrtf(tot), 1e-12f);
  }
}

// ---------------------------------------------------------------- K5: Gram partials (unchanged)
__global__ __launch_bounds__(256) void k_gram(
    const float* __restrict__ qbuf, const float* __restrict__ kbuf,
    float* __restrict__ part)
{
  __shared__ float sq[32 * 65], sk[32 * 65];
  int blk = blockIdx.x;
  int split = blk / 12, r = blk % 12;
  int b = r / 6, hh = r % 6;
  int n0 = split * 384;
  int t = threadIdx.x;
  int c = t >> 3, dg = t & 7;
  float acc[4] = {};
  for (int sc = 0; sc < 6; ++sc) {
    __syncthreads();
    for (int i = t; i < 2048; i += 256) {
      int cc = i >> 6, j = i & 63;
      size_t g = (size_t)(b * 192 + hh * 32 + cc) * 9216 + n0 + sc * 64 + j;
      sq[cc * 65 + j] = qbuf[g];
      sk[cc * 65 + j] = kbuf[g];
    }
    __syncthreads();
#pragma unroll 8
    for (int j = 0; j < 64; ++j) {
      float qv = sq[c * 65 + j];
#pragma unroll
      for (int i2 = 0; i2 < 4; ++i2)
        acc[i2] += qv * sk[(dg * 4 + i2) * 65 + j];
    }
  }
  float* dst = &part[((size_t)split * 12 + b * 6 + hh) * 1024 + c * 32 + dg * 4];
  *(float4*)dst = {acc[0], acc[1], acc[2], acc[3]};
}

// ---------------------------------------------------------------- K6: softmax (unchanged)
__global__ __launch_bounds__(1024) void k_softmax(
    const float* __restrict__ part, const float* __restrict__ nq,
    const float* __restrict__ nk, const float* __restrict__ temp,
    float* __restrict__ attn)
{
  int bi = blockIdx.x;
  int b = bi / 6, h = bi % 6;
  int t = threadIdx.x;
  int c = t >> 5, d = t & 31;
  float val = 0.f;
  for (int s = 0; s < SPLITS; ++s) val += part[((size_t)s * 12 + bi) * 1024 + t];
  val *= nq[b * 192 + h * 32 + c] * nk[b * 192 + h * 32 + d] * temp[h];
  float m = val;
#pragma unroll
  for (int o = 16; o; o >>= 1) m = fmaxf(m, __shfl_xor(m, o));
  float e = expf(val - m);
  float s = e;
#pragma unroll
  for (int o = 16; o; o >>= 1) s += __shfl_xor(s, o);
  attn[(size_t)bi * 1024 + t] = e / s;
}

// ---------------------------------------------------------------- K7: W2 = proj . blockdiag(attn) (unchanged)
__global__ __launch_bounds__(256) void k_w2(
    const float* __restrict__ attn, const float* __restrict__ projw,
    float* __restrict__ w2)
{
  __shared__ float sa[32 * 33];
  int bi = blockIdx.x;
  int b = bi / 6, h = bi % 6;
  int t = threadIdx.x;
  for (int i = t; i < 1024; i += 256)
    sa[(i >> 5) * 33 + (i & 31)] = attn[(size_t)bi * 1024 + i];
  __syncthreads();
  for (int e = t; e < 6144; e += 256) {
    int o = e >> 5, d = e & 31;
    float s = 0.f;
#pragma unroll 8
    for (int ci = 0; ci < 32; ++ci)
      s += projw[o * 192 + h * 32 + ci] * sa[ci * 33 + d];
    w2[((size_t)b * 192 + o) * 192 + h * 32 + d] = s;
  }
}

// ---------------------------------------------------------------- K8: out = W2 @ v (unchanged)
__global__ __launch_bounds__(384) void k_out(
    const float* __restrict__ vbuf, const float* __restrict__ w2,
    float* __restrict__ out)
{
  __shared__ __align__(16) float Al[16 * 196];
  __shared__ __align__(16) float Bl[16 * 32];
  int blk = blockIdx.x;
  int b = blk / 288;
  int pix0 = (blk % 288) * 32;
  int t = threadIdx.x;
  int og = t >> 3, pg = t & 7;
  float acc[4][4] = {};
  float ra[8], rb2[2];
#pragma unroll
  for (int i = 0; i < 8; ++i) {
    int e = t + i * 384;
    ra[i] = w2[(size_t)(b * 192 + (e >> 4)) * 192 + (e & 15)];
  }
#pragma unroll
  for (int i = 0; i < 2; ++i) {
    int e = t + i * 384;
    rb2[i] = (e < 512) ? vbuf[(size_t)(b * 192 + (e >> 5)) * 9216 + pix0 + (e & 31)] : 0.f;
  }
  for (int c0 = 0; c0 < 192; c0 += 16) {
#pragma unroll
    for (int i = 0; i < 8; ++i) {
      int e = t + i * 384;
      Al[(e & 15) * 196 + (e >> 4)] = ra[i];
    }
#pragma unroll
    for (int i = 0; i < 2; ++i) {
      int e = t + i * 384;
      if (e < 512) Bl[e] = rb2[i];
    }
    __syncthreads();
    if (c0 + 16 < 192) {
#pragma unroll
      for (int i = 0; i < 8; ++i) {
        int e = t + i * 384;
        ra[i] = w2[(size_t)(b * 192 + (e >> 4)) * 192 + c0 + 16 + (e & 15)];
      }
#pragma unroll
      for (int i = 0; i < 2; ++i) {
        int e = t + i * 384;
        rb2[i] = (e < 512) ? vbuf[(size_t)(b * 192 + c0 + 16 + (e >> 5)) * 9216 + pix0 + (e & 31)] : 0.f;
      }
    }
    const float4* B4 = (const float4*)Bl;
    const float4* A4 = (const float4*)Al;
#pragma unroll
    for (int k = 0; k < 16; ++k) {
      float4 bv = B4[k * 8 + pg];
      float4 va = A4[k * 49 + og];
      float av[4] = {va.x, va.y, va.z, va.w};
#pragma unroll
      for (int i = 0; i < 4; ++i) {
        acc[i][0] += av[i] * bv.x; acc[i][1] += av[i] * bv.y;
        acc[i][2] += av[i] * bv.z; acc[i][3] += av[i] * bv.w;
      }
    }
    __syncthreads();
  }
#pragma unroll
  for (int i = 0; i < 4; ++i) {
    int o = og * 4 + i;
    *(float4*)&out[(size_t)(b * 192 + o) * 9216 + pix0 + pg * 4]
        = {acc[i][0], acc[i][1], acc[i][2], acc[i][3]};
  }
}

// ----------------------------------------------------------------
extern "C" void kernel_launch(void* const* d_in, const int* in_sizes, int n_in,
                              void* d_out, int out_size, void* d_ws, size_t ws_size,
                              hipStream_t stream) {
  (void)in_sizes; (void)n_in; (void)out_size; (void)ws_size;
  const float* x     = (const float*)d_in[0];
  const float* pw    = (const float*)d_in[1];
  const float* pb    = (const float*)d_in[2];
  const float* dw    = (const float*)d_in[3];
  const float* qkvw  = (const float*)d_in[4];
  const float* projw = (const float*)d_in[5];
  const float* temp  = (const float*)d_in[6];
  float* ws   = (float*)d_ws;
  float* off  = ws + OFF_OFS;
  float* qb   = ws + Q_OFS;
  float* kb   = ws + K_OFS;
  float* vb   = ws + V_OFS;
  float* nq   = ws + NQ_OFS;
  float* nk   = ws + NK_OFS;
  float* part = ws + PART_OFS;
  float* attn = ws + ATTN_OFS;
  float* w2   = ws + W2_OFS;
  float* opart = ws + XOFF_OFS;                 // offc partials, then xofft
  unsigned*       xoffu = (unsigned*)(ws + XOFF_OFS);
  unsigned short* xofft = (unsigned short*)xoffu;
  unsigned short* wbt   = (unsigned short*)(ws + WBT_OFS);
  float* out  = (float*)d_out;

  k_offc_part  <<<dim3(1152), dim3(192), 0, stream>>>(x, pw, opart);
  k_offc_red   <<<dim3(648),  dim3(256), 0, stream>>>((const float4*)opart, pb, (float4*)off);
  k_cvtw       <<<dim3(324),  dim3(256), 0, stream>>>((const float4*)dw, (uint2*)wbt, 82944);
  k_qkv        <<<dim3(576),  dim3(384), 0, stream>>>(x, qkvw, kb, vb);
  for (int b = 0; b < 2; ++b) {
    k_sample   <<<dim3(1152), dim3(256), 0, stream>>>(x, off, xoffu, b);
    k_dgemm    <<<dim3(1152), dim3(64),  0, stream>>>(xofft, wbt, qb, b);
  }
  k_norms      <<<dim3(768),  dim3(256), 0, stream>>>(qb, kb, nq, nk);
  k_gram       <<<dim3(288),  dim3(256), 0, stream>>>(qb, kb, part);
  k_softmax    <<<dim3(12),   dim3(1024),0, stream>>>(part, nq, nk, temp, attn);
  k_w2         <<<dim3(12),   dim3(256), 0, stream>>>(attn, projw, w2);
  k_out        <<<dim3(576),  dim3(384), 0, stream>>>(vb, w2, out);
}

// Round 8
// 412.959 us; speedup vs baseline: 2.9688x; 1.1671x over previous
//
#include <hip/hip_runtime.h>

// MSDformer: deformable conv (q) + transposed-channel attention + proj.
// R8: k_qkv -> bf16 MFMA (k bf16 out, v fp32 out); k_gram -> bf16 MFMA over
// bf16 q/k [c][pix] (pix-contiguous = MFMA K); q stored bf16; norms read bf16.
constexpr int SPLITS = 24;                             // legacy offset math only
constexpr int GSPL   = 48;                             // gram splits
constexpr size_t OFF_OFS  = 0;                         // [2][18][9216] f32
constexpr size_t Q_OFS    = 331776;                    // [2][192][9216] bf16 (half of f32 region)
constexpr size_t QKVWBF_OFS = Q_OFS + 1769472;         // [384][192] bf16 in Q-region hole
constexpr size_t K_OFS    = Q_OFS + 3538944;           // [2][192][9216] bf16
constexpr size_t PART2_OFS = K_OFS + 1769472;          // [48][12][1024] f32 in K-region hole
constexpr size_t V_OFS    = K_OFS + 3538944;           // [2][192][9216] f32
constexpr size_t NQ_OFS   = V_OFS + 3538944;           // [2*192] inv-norms
constexpr size_t NK_OFS   = NQ_OFS + 384;
constexpr size_t PART_OFS = NK_OFS + 384;              // (unused, legacy)
constexpr size_t ATTN_OFS = PART_OFS + (size_t)SPLITS * 12 * 1024;  // [12][1024]
constexpr size_t W2_OFS   = ATTN_OFS + 12288;          // [2][192][192]
constexpr size_t XOFF_OFS = 11330304;                  // [9216][1728] bf16 == offc partials [12][663552] f32
constexpr size_t WBT_OFS  = XOFF_OFS + 7962624;        // [192][1728] bf16
// total ws: 19,458,816 floats = 77.8 MB (unchanged)

typedef __attribute__((ext_vector_type(8))) short bf16x8;
typedef __attribute__((ext_vector_type(4))) float f32x4;

__device__ __forceinline__ unsigned bf16rne(float f) {
  unsigned u = __float_as_uint(f);
  return (u + 0x7fffu + ((u >> 16) & 1u)) >> 16;
}
__device__ __forceinline__ float bf2f(unsigned hw) {
  return __uint_as_float(hw << 16);
}

// ---------------------------------------------------------------- K1a: offset conv partials
__global__ __launch_bounds__(192) void k_offc_part(
    const float* __restrict__ x, const float* __restrict__ pw,
    float* __restrict__ part)
{
  __shared__ float band[16 * 4 * 98];          // [cc][row 4][col 98]
  int blk = blockIdx.x;
  int csp = blk % 12;
  int rem = blk / 12;
  int b  = rem / 48;
  int r0 = (rem % 48) * 2;
  int c0 = csp * 16;
  int t  = threadIdx.x;
  int r = t / 96, w = t % 96;

  for (int i = 0; i < 33; ++i) {
    int e = t + i * 192;
    if (e < 6272) {
      int cc = e / 392, r2 = e % 392;
      int row = r2 / 98, col = r2 % 98;
      int gr = r0 + row - 1, gc = col - 1;
      float v = 0.f;
      if (gr >= 0 && gr < 96 && gc >= 0 && gc < 96)
        v = x[((b * 192 + c0 + cc) * 96 + gr) * 96 + gc];
      band[cc * 392 + row * 98 + col] = v;
    }
  }
  __syncthreads();

  float acc[18] = {};
#pragma unroll 4
  for (int cc = 0; cc < 16; ++cc) {
    float bv[9];
#pragma unroll
    for (int ki = 0; ki < 3; ++ki)
#pragma unroll
      for (int kj = 0; kj < 3; ++kj)
        bv[ki * 3 + kj] = band[cc * 392 + (r + ki) * 98 + w + kj];
#pragma unroll
    for (int o = 0; o < 18; ++o) {
      float w9[9];
#pragma unroll
      for (int kk = 0; kk < 9; ++kk)        // wave-uniform -> s_load
        w9[kk] = pw[(o * 192 + c0 + cc) * 9 + kk];
#pragma unroll
      for (int kk = 0; kk < 9; ++kk)
        acc[o] += w9[kk] * bv[kk];
    }
  }
  float* dst = &part[(size_t)csp * 663552 + ((size_t)(b * 18) * 96 + r0 + r) * 96 + w];
#pragma unroll
  for (int o = 0; o < 18; ++o)
    dst[(size_t)o * 9216] = acc[o];
}

// ---------------------------------------------------------------- K1b: reduce partials + bias
__global__ __launch_bounds__(256) void k_offc_red(
    const float4* __restrict__ part4, const float* __restrict__ pb,
    float4* __restrict__ off4)
{
  int i4 = blockIdx.x * 256 + threadIdx.x;
  if (i4 >= 165888) return;
  int o = ((i4 * 4) / 9216) % 18;
  float bb = pb[o];
  float4 s = {bb, bb, bb, bb};
  for (int sp = 0; sp < 12; ++sp) {
    float4 v = part4[(size_t)sp * 165888 + i4];
    s.x += v.x; s.y += v.y; s.z += v.z; s.w += v.w;
  }
  off4[i4] = s;
}

// ---------------------------------------------------------------- K2a: fp32->bf16 converters
__global__ __launch_bounds__(256) void k_cvtw(
    const float4* __restrict__ dw4, uint2* __restrict__ out, int n4)
{
  int i = blockIdx.x * 256 + threadIdx.x;
  if (i < n4) {
    float4 v = dw4[i];
    out[i] = uint2{bf16rne(v.x) | (bf16rne(v.y) << 16),
                   bf16rne(v.z) | (bf16rne(v.w) << 16)};
  }
}
// qkvw rows 192..575 -> wq[384][192] bf16
__global__ __launch_bounds__(256) void k_cvtqkvw(
    const float* __restrict__ qkvw, unsigned* __restrict__ wqu)
{
  int i = blockIdx.x * 256 + threadIdx.x;
  if (i < 36864)
    wqu[i] = bf16rne(qkvw[36864 + 2 * i]) | (bf16rne(qkvw[36864 + 2 * i + 1]) << 16);
}

// ---------------------------------------------------------------- K3: [k;v] = Wqkv(bf16) @ x(bf16) via MFMA
// grid 4608 = B x 288 pixtiles x 8 otiles(48); block 64 (1 wave).
// B-tile (192c x 32px) staged to LDS as bf16 pairs [px][cp], stride 100 dwords
// (16B-aligned b128 reads, 2-way bank alias only). k rows -> bf16; v rows -> f32.
__global__ __launch_bounds__(64) void k_qkv_mfma(
    const float* __restrict__ x, const unsigned short* __restrict__ wq,
    unsigned short* __restrict__ kbf, float* __restrict__ vbuf)
{
  __shared__ unsigned Bl[32 * 100];
  int id = blockIdx.x;
  int b  = id / 2304;
  int rem = id % 2304;
  int og = rem & 7;
  int pt = rem >> 3;
  int pix0 = pt * 32;
  int l = threadIdx.x;
  int lo = l & 15, hi = l >> 4;

  const float* xb = x + (size_t)b * 192 * 9216 + pix0;
  for (int i = 0; i < 48; ++i) {
    int e = l + i * 64;
    int cp = e >> 5, px = e & 31;
    float x0 = xb[(size_t)(2 * cp) * 9216 + px];
    float x1 = xb[(size_t)(2 * cp + 1) * 9216 + px];
    Bl[px * 100 + cp] = bf16rne(x0) | (bf16rne(x1) << 16);
  }
  __syncthreads();

  const unsigned short* A0 = wq + (og * 48 + lo) * 192 + hi * 8;
  const unsigned short* A1 = A0 + 16 * 192;
  const unsigned short* A2 = A0 + 32 * 192;
  const unsigned* B0 = &Bl[lo * 100 + hi * 4];
  const unsigned* B1 = &Bl[(16 + lo) * 100 + hi * 4];
  f32x4 acc00 = {}, acc01 = {}, acc10 = {}, acc11 = {}, acc20 = {}, acc21 = {};
#pragma unroll
  for (int ks = 0; ks < 6; ++ks) {
    bf16x8 av0 = *(const bf16x8*)(A0 + ks * 32);
    bf16x8 av1 = *(const bf16x8*)(A1 + ks * 32);
    bf16x8 av2 = *(const bf16x8*)(A2 + ks * 32);
    bf16x8 bv0 = *(const bf16x8*)(B0 + ks * 16);
    bf16x8 bv1 = *(const bf16x8*)(B1 + ks * 16);
    acc00 = __builtin_amdgcn_mfma_f32_16x16x32_bf16(av0, bv0, acc00, 0, 0, 0);
    acc01 = __builtin_amdgcn_mfma_f32_16x16x32_bf16(av0, bv1, acc01, 0, 0, 0);
    acc10 = __builtin_amdgcn_mfma_f32_16x16x32_bf16(av1, bv0, acc10, 0, 0, 0);
    acc11 = __builtin_amdgcn_mfma_f32_16x16x32_bf16(av1, bv1, acc11, 0, 0, 0);
    acc20 = __builtin_amdgcn_mfma_f32_16x16x32_bf16(av2, bv0, acc20, 0, 0, 0);
    acc21 = __builtin_amdgcn_mfma_f32_16x16x32_bf16(av2, bv1, acc21, 0, 0, 0);
  }
  f32x4* accs[3][2] = {{&acc00, &acc01}, {&acc10, &acc11}, {&acc20, &acc21}};
#pragma unroll
  for (int fo = 0; fo < 3; ++fo)
#pragma unroll
    for (int fp = 0; fp < 2; ++fp)
#pragma unroll
      for (int r = 0; r < 4; ++r) {
        int o = og * 48 + fo * 16 + hi * 4 + r;
        int px = pix0 + fp * 16 + lo;
        float vv = (*accs[fo][fp])[r];
        if (o < 192)
          kbf[(size_t)(b * 192 + o) * 9216 + px] = (unsigned short)bf16rne(vv);
        else
          vbuf[(size_t)(b * 192 + (o - 192)) * 9216 + px] = vv;
      }
}

// ---------------------------------------------------------------- K4: direct-gather sample -> xofft[pix][k] bf16
__global__ __launch_bounds__(256) void k_sample(
    const float* __restrict__ x, const float* __restrict__ off,
    unsigned* __restrict__ xoffu, int b)
{
  __shared__ float twt[4][288];
  __shared__ int   tof[4][288];
  int blk = blockIdx.x;
  int csp = blk & 3;
  int tile = blk >> 2;
  int h  = tile / 3;
  int w0 = (tile % 3) * 32;
  int t  = threadIdx.x;

  for (int e = t; e < 288; e += 256) {
    int n = e >> 5, pix = e & 31;
    int ki = n / 3, kj = n % 3;
    int w = w0 + pix;
    float ox = off[((b * 18 + n) * 96 + h) * 96 + w];
    float oy = off[((b * 18 + 9 + n) * 96 + h) * 96 + w];
    float px = (float)(h + ki) + ox;
    float py = (float)(w + kj) + oy;
    float fx = floorf(px), fy = floorf(py);
    int qx0 = max(0, min(97, (int)fx));
    int qx1 = max(0, min(97, (int)fx + 1));
    int qy0 = max(0, min(97, (int)fy));
    int qy1 = max(0, min(97, (int)fy + 1));
    float pxc = fminf(fmaxf(px, 0.f), 97.f);
    float pyc = fminf(fmaxf(py, 0.f), 97.f);
    float wx0 = 1.f + ((float)qx0 - pxc);
    float wx1 = 1.f - ((float)qx1 - pxc);
    float wy0 = 1.f + ((float)qy0 - pyc);
    float wy1 = 1.f - ((float)qy1 - pyc);
    int X0 = qx0 - 1, X1 = qx1 - 1, Y0 = qy0 - 1, Y1 = qy1 - 1;
    bool vX0 = (unsigned)X0 < 96u, vX1 = (unsigned)X1 < 96u;
    bool vY0 = (unsigned)Y0 < 96u, vY1 = (unsigned)Y1 < 96u;
    twt[0][e] = (vX0 && vY0) ? wx0 * wy0 : 0.f;
    tof[0][e] = (vX0 && vY0) ? X0 * 96 + Y0 : 0;
    twt[1][e] = (vX1 && vY1) ? wx1 * wy1 : 0.f;
    tof[1][e] = (vX1 && vY1) ? X1 * 96 + Y1 : 0;
    twt[2][e] = (vX0 && vY1) ? wx0 * wy1 : 0.f;
    tof[2][e] = (vX0 && vY1) ? X0 * 96 + Y1 : 0;
    twt[3][e] = (vX1 && vY0) ? wx1 * wy0 : 0.f;
    tof[3][e] = (vX1 && vY0) ? X1 * 96 + Y0 : 0;
  }
  __syncthreads();

  int px = t & 31, cg = t >> 5;
  int c0 = csp * 48 + cg * 6;
  const float* bas = x + (size_t)(b * 192 + c0) * 9216;
  unsigned pixg = (unsigned)(h * 96 + w0 + px);
  for (int cp = 0; cp < 3; ++cp) {
    float vv[2][9];
#pragma unroll
    for (int n = 0; n < 9; ++n) {
      int e2 = n * 32 + px;
      float wlt = twt[0][e2], wrb = twt[1][e2], wlb = twt[2][e2], wrt = twt[3][e2];
      int olt = tof[0][e2], orb = tof[1][e2], olb = tof[2][e2], ort = tof[3][e2];
      const float* b0 = bas + cp * 2 * 9216;
      const float* b1 = b0 + 9216;
      vv[0][n] = wlt * b0[olt] + wrb * b0[orb] + wlb * b0[olb] + wrt * b0[ort];
      vv[1][n] = wlt * b1[olt] + wrb * b1[orb] + wlb * b1[olb] + wrt * b1[ort];
    }
    unsigned baseDW = (pixg * 1728u + (unsigned)(c0 + cp * 2) * 9u) >> 1;
#pragma unroll
    for (int jj = 0; jj < 9; ++jj) {
      constexpr int idx0[9] = {0,0,0,0,0,1,1,1,1};
      constexpr int idx1[9] = {0,0,0,0,1,1,1,1,1};
      xoffu[baseDW + jj] = bf16rne(vv[idx0[jj]][(2 * jj) % 9])
                         | (bf16rne(vv[idx1[jj]][(2 * jj + 1) % 9]) << 16);
    }
  }
}

// ---------------------------------------------------------------- K5: q = W(bf16) @ xofft(bf16), MFMA; q stored bf16
__global__ __launch_bounds__(64) void k_dgemm(
    const unsigned short* __restrict__ xofft, const unsigned short* __restrict__ wbt,
    unsigned short* __restrict__ qbf, int b)
{
  int blk = blockIdx.x;
  int og = blk & 3;
  int pt = blk >> 2;
  int l  = threadIdx.x;
  int lo = l & 15, hi = l >> 4;
  const char* X = (const char*)xofft;
  const char* W = (const char*)wbt;
  size_t a0 = ((size_t)(og * 48 + lo)      * 1728 + hi * 8) * 2;
  size_t a1 = ((size_t)(og * 48 + 16 + lo) * 1728 + hi * 8) * 2;
  size_t a2 = ((size_t)(og * 48 + 32 + lo) * 1728 + hi * 8) * 2;
  size_t b0 = ((size_t)(pt * 32 + lo)      * 1728 + hi * 8) * 2;
  size_t b1 = ((size_t)(pt * 32 + 16 + lo) * 1728 + hi * 8) * 2;
  f32x4 acc00 = {}, acc01 = {}, acc10 = {}, acc11 = {}, acc20 = {}, acc21 = {};
#pragma unroll 2
  for (int k0 = 0; k0 < 3456; k0 += 64) {
    bf16x8 av0 = *(const bf16x8*)(W + a0 + k0);
    bf16x8 av1 = *(const bf16x8*)(W + a1 + k0);
    bf16x8 av2 = *(const bf16x8*)(W + a2 + k0);
    bf16x8 bv0 = *(const bf16x8*)(X + b0 + k0);
    bf16x8 bv1 = *(const bf16x8*)(X + b1 + k0);
    acc00 = __builtin_amdgcn_mfma_f32_16x16x32_bf16(av0, bv0, acc00, 0, 0, 0);
    acc01 = __builtin_amdgcn_mfma_f32_16x16x32_bf16(av0, bv1, acc01, 0, 0, 0);
    acc10 = __builtin_amdgcn_mfma_f32_16x16x32_bf16(av1, bv0, acc10, 0, 0, 0);
    acc11 = __builtin_amdgcn_mfma_f32_16x16x32_bf16(av1, bv1, acc11, 0, 0, 0);
    acc20 = __builtin_amdgcn_mfma_f32_16x16x32_bf16(av2, bv0, acc20, 0, 0, 0);
    acc21 = __builtin_amdgcn_mfma_f32_16x16x32_bf16(av2, bv1, acc21, 0, 0, 0);
  }
  f32x4* accs[3][2] = {{&acc00, &acc01}, {&acc10, &acc11}, {&acc20, &acc21}};
#pragma unroll
  for (int fo = 0; fo < 3; ++fo)
#pragma unroll
    for (int fp = 0; fp < 2; ++fp)
#pragma unroll
      for (int r = 0; r < 4; ++r)
        qbf[(size_t)(b * 192 + og * 48 + fo * 16 + hi * 4 + r) * 9216
            + pt * 32 + fp * 16 + lo] = (unsigned short)bf16rne((*accs[fo][fp])[r]);
}

// ---------------------------------------------------------------- K6: inv L2 norms from bf16 rows
__global__ __launch_bounds__(256) void k_norms(
    const unsigned short* __restrict__ qbf, const unsigned short* __restrict__ kbf,
    float* __restrict__ nq, float* __restrict__ nk)
{
  __shared__ float red[4];
  int blk = blockIdx.x;
  int which = blk / 384, r = blk % 384;
  const uint4* s4 = (const uint4*)((which ? kbf : qbf) + (size_t)r * 9216);
  int t = threadIdx.x;
  float s = 0.f;
  for (int i = t; i < 1152; i += 256) {
    uint4 v = s4[i];
    unsigned ws_[4] = {v.x, v.y, v.z, v.w};
#pragma unroll
    for (int j = 0; j < 4; ++j) {
      float a = bf2f(ws_[j] & 0xffffu);
      float bq = __uint_as_float(ws_[j] & 0xffff0000u);
      s += a * a + bq * bq;
    }
  }
#pragma unroll
  for (int o = 32; o; o >>= 1) s += __shfl_xor(s, o);
  if ((t & 63) == 0) red[t >> 6] = s;
  __syncthreads();
  if (t == 0) {
    float tot = red[0] + red[1] + red[2] + red[3];
    (which ? nk : nq)[r] = 1.f / fmaxf(sqrtf(tot), 1e-12f);
  }
}

// ---------------------------------------------------------------- K7: Gram partials via MFMA
// grid 576 = 48 splits x 12(b,h); block 64. gram[c][d] partial over 192 pix.
__global__ __launch_bounds__(64) void k_gram_mfma(
    const unsigned short* __restrict__ qbf, const unsigned short* __restrict__ kbf,
    float* __restrict__ part2)
{
  int blk = blockIdx.x;
  int split = blk / 12, r = blk % 12;
  int b = r / 6, hh = r % 6;
  int n0 = split * 192;
  int l = threadIdx.x;
  int lo = l & 15, hi = l >> 4;
  const unsigned short* Q0 = qbf + (size_t)(b * 192 + hh * 32 + lo) * 9216 + n0 + hi * 8;
  const unsigned short* Q1 = Q0 + (size_t)16 * 9216;
  const unsigned short* K0 = kbf + (size_t)(b * 192 + hh * 32 + lo) * 9216 + n0 + hi * 8;
  const unsigned short* K1 = K0 + (size_t)16 * 9216;
  f32x4 g00 = {}, g01 = {}, g10 = {}, g11 = {};
#pragma unroll
  for (int ks = 0; ks < 6; ++ks) {
    bf16x8 qa0 = *(const bf16x8*)(Q0 + ks * 32);
    bf16x8 qa1 = *(const bf16x8*)(Q1 + ks * 32);
    bf16x8 kb0 = *(const bf16x8*)(K0 + ks * 32);
    bf16x8 kb1 = *(const bf16x8*)(K1 + ks * 32);
    g00 = __builtin_amdgcn_mfma_f32_16x16x32_bf16(qa0, kb0, g00, 0, 0, 0);
    g01 = __builtin_amdgcn_mfma_f32_16x16x32_bf16(qa0, kb1, g01, 0, 0, 0);
    g10 = __builtin_amdgcn_mfma_f32_16x16x32_bf16(qa1, kb0, g10, 0, 0, 0);
    g11 = __builtin_amdgcn_mfma_f32_16x16x32_bf16(qa1, kb1, g11, 0, 0, 0);
  }
  float* dst = part2 + ((size_t)split * 12 + r) * 1024;
  f32x4* gs[2][2] = {{&g00, &g01}, {&g10, &g11}};
#pragma unroll
  for (int fc = 0; fc < 2; ++fc)
#pragma unroll
    for (int fd = 0; fd < 2; ++fd)
#pragma unroll
      for (int rr = 0; rr < 4; ++rr)
        dst[(fc * 16 + hi * 4 + rr) * 32 + fd * 16 + lo] = (*gs[fc][fd])[rr];
}

// ---------------------------------------------------------------- K8: reduce + scale + softmax(d)
__global__ __launch_bounds__(1024) void k_softmax(
    const float* __restrict__ part2, const float* __restrict__ nq,
    const float* __restrict__ nk, const float* __restrict__ temp,
    float* __restrict__ attn)
{
  int bi = blockIdx.x;
  int b = bi / 6, h = bi % 6;
  int t = threadIdx.x;
  int c = t >> 5, d = t & 31;
  float val = 0.f;
  for (int s = 0; s < GSPL; ++s) val += part2[((size_t)s * 12 + bi) * 1024 + t];
  val *= nq[b * 192 + h * 32 + c] * nk[b * 192 + h * 32 + d] * temp[h];
  float m = val;
#pragma unroll
  for (int o = 16; o; o >>= 1) m = fmaxf(m, __shfl_xor(m, o));
  float e = expf(val - m);
  float s = e;
#pragma unroll
  for (int o = 16; o; o >>= 1) s += __shfl_xor(s, o);
  attn[(size_t)bi * 1024 + t] = e / s;
}

// ---------------------------------------------------------------- K9: W2 = proj . blockdiag(attn)
__global__ __launch_bounds__(256) void k_w2(
    const float* __restrict__ attn, const float* __restrict__ projw,
    float* __restrict__ w2)
{
  __shared__ float sa[32 * 33];
  int bi = blockIdx.x;
  int b = bi / 6, h = bi % 6;
  int t = threadIdx.x;
  for (int i = t; i < 1024; i += 256)
    sa[(i >> 5) * 33 + (i & 31)] = attn[(size_t)bi * 1024 + i];
  __syncthreads();
  for (int e = t; e < 6144; e += 256) {
    int o = e >> 5, d = e & 31;
    float s = 0.f;
#pragma unroll 8
    for (int ci = 0; ci < 32; ++ci)
      s += projw[o * 192 + h * 32 + ci] * sa[ci * 33 + d];
    w2[((size_t)b * 192 + o) * 192 + h * 32 + d] = s;
  }
}

// ---------------------------------------------------------------- K10: out = W2 @ v (fp32, unchanged)
__global__ __launch_bounds__(384) void k_out(
    const float* __restrict__ vbuf, const float* __restrict__ w2,
    float* __restrict__ out)
{
  __shared__ __align__(16) float Al[16 * 196];
  __shared__ __align__(16) float Bl[16 * 32];
  int blk = blockIdx.x;
  int b = blk / 288;
  int pix0 = (blk % 288) * 32;
  int t = threadIdx.x;
  int og = t >> 3, pg = t & 7;
  float acc[4][4] = {};
  float ra[8], rb2[2];
#pragma unroll
  for (int i = 0; i < 8; ++i) {
    int e = t + i * 384;
    ra[i] = w2[(size_t)(b * 192 + (e >> 4)) * 192 + (e & 15)];
  }
#pragma unroll
  for (int i = 0; i < 2; ++i) {
    int e = t + i * 384;
    rb2[i] = (e < 512) ? vbuf[(size_t)(b * 192 + (e >> 5)) * 9216 + pix0 + (e & 31)] : 0.f;
  }
  for (int c0 = 0; c0 < 192; c0 += 16) {
#pragma unroll
    for (int i = 0; i < 8; ++i) {
      int e = t + i * 384;
      Al[(e & 15) * 196 + (e >> 4)] = ra[i];
    }
#pragma unroll
    for (int i = 0; i < 2; ++i) {
      int e = t + i * 384;
      if (e < 512) Bl[e] = rb2[i];
    }
    __syncthreads();
    if (c0 + 16 < 192) {
#pragma unroll
      for (int i = 0; i < 8; ++i) {
        int e = t + i * 384;
        ra[i] = w2[(size_t)(b * 192 + (e >> 4)) * 192 + c0 + 16 + (e & 15)];
      }
#pragma unroll
      for (int i = 0; i < 2; ++i) {
        int e = t + i * 384;
        rb2[i] = (e < 512) ? vbuf[(size_t)(b * 192 + c0 + 16 + (e >> 5)) * 9216 + pix0 + (e & 31)] : 0.f;
      }
    }
    const float4* B4 = (const float4*)Bl;
    const float4* A4 = (const float4*)Al;
#pragma unroll
    for (int k = 0; k < 16; ++k) {
      float4 bv = B4[k * 8 + pg];
      float4 va = A4[k * 49 + og];
      float av[4] = {va.x, va.y, va.z, va.w};
#pragma unroll
      for (int i = 0; i < 4; ++i) {
        acc[i][0] += av[i] * bv.x; acc[i][1] += av[i] * bv.y;
        acc[i][2] += av[i] * bv.z; acc[i][3] += av[i] * bv.w;
      }
    }
    __syncthreads();
  }
#pragma unroll
  for (int i = 0; i < 4; ++i) {
    int o = og * 4 + i;
    *(float4*)&out[(size_t)(b * 192 + o) * 9216 + pix0 + pg * 4]
        = {acc[i][0], acc[i][1], acc[i][2], acc[i][3]};
  }
}

// ----------------------------------------------------------------
extern "C" void kernel_launch(void* const* d_in, const int* in_sizes, int n_in,
                              void* d_out, int out_size, void* d_ws, size_t ws_size,
                              hipStream_t stream) {
  (void)in_sizes; (void)n_in; (void)out_size; (void)ws_size;
  const float* x     = (const float*)d_in[0];
  const float* pw    = (const float*)d_in[1];
  const float* pb    = (const float*)d_in[2];
  const float* dw    = (const float*)d_in[3];
  const float* qkvw  = (const float*)d_in[4];
  const float* projw = (const float*)d_in[5];
  const float* temp  = (const float*)d_in[6];
  float* ws   = (float*)d_ws;
  float* off  = ws + OFF_OFS;
  unsigned short* qbf = (unsigned short*)(ws + Q_OFS);
  unsigned*       wqu = (unsigned*)(ws + QKVWBF_OFS);
  unsigned short* wq  = (unsigned short*)wqu;
  unsigned short* kbf = (unsigned short*)(ws + K_OFS);
  float* part2 = ws + PART2_OFS;
  float* vb   = ws + V_OFS;
  float* nq   = ws + NQ_OFS;
  float* nk   = ws + NK_OFS;
  float* attn = ws + ATTN_OFS;
  float* w2   = ws + W2_OFS;
  float* opart = ws + XOFF_OFS;                 // offc partials, then xofft
  unsigned*       xoffu = (unsigned*)(ws + XOFF_OFS);
  unsigned short* xofft = (unsigned short*)xoffu;
  unsigned short* wbt   = (unsigned short*)(ws + WBT_OFS);
  float* out  = (float*)d_out;

  k_offc_part  <<<dim3(1152), dim3(192), 0, stream>>>(x, pw, opart);
  k_offc_red   <<<dim3(648),  dim3(256), 0, stream>>>((const float4*)opart, pb, (float4*)off);
  k_cvtw       <<<dim3(324),  dim3(256), 0, stream>>>((const float4*)dw, (uint2*)wbt, 82944);
  k_cvtqkvw    <<<dim3(144),  dim3(256), 0, stream>>>(qkvw, wqu);
  k_qkv_mfma   <<<dim3(4608), dim3(64),  0, stream>>>(x, wq, kbf, vb);
  for (int b = 0; b < 2; ++b) {
    k_sample   <<<dim3(1152), dim3(256), 0, stream>>>(x, off, xoffu, b);
    k_dgemm    <<<dim3(1152), dim3(64),  0, stream>>>(xofft, wbt, qbf, b);
  }
  k_norms      <<<dim3(768),  dim3(256), 0, stream>>>(qbf, kbf, nq, nk);
  k_gram_mfma  <<<dim3(576),  dim3(64),  0, stream>>>(qbf, kbf, part2);
  k_softmax    <<<dim3(12),   dim3(1024),0, stream>>>(part2, nq, nk, temp, attn);
  k_w2         <<<dim3(12),   dim3(256), 0, stream>>>(attn, projw, w2);
  k_out        <<<dim3(576),  dim3(384), 0, stream>>>(vb, w2, out);
}

// Round 9
// 393.850 us; speedup vs baseline: 3.1128x; 1.0485x over previous
//
#include <hip/hip_runtime.h>

// MSDformer: deformable conv (q) + transposed-channel attention + proj.
// R9: k_sample writes staged via LDS -> coalesced global stores (was 3456-B
// strided per lane, 660 GB/s pacing); per-tap table hoisting; VGPR diet.
constexpr int SPLITS = 24;                             // legacy offset math only
constexpr int GSPL   = 48;                             // gram splits
constexpr size_t OFF_OFS  = 0;                         // [2][18][9216] f32
constexpr size_t Q_OFS    = 331776;                    // [2][192][9216] bf16 (half of f32 region)
constexpr size_t QKVWBF_OFS = Q_OFS + 1769472;         // [384][192] bf16 in Q-region hole
constexpr size_t K_OFS    = Q_OFS + 3538944;           // [2][192][9216] bf16
constexpr size_t PART2_OFS = K_OFS + 1769472;          // [48][12][1024] f32 in K-region hole
constexpr size_t V_OFS    = K_OFS + 3538944;           // [2][192][9216] f32
constexpr size_t NQ_OFS   = V_OFS + 3538944;           // [2*192] inv-norms
constexpr size_t NK_OFS   = NQ_OFS + 384;
constexpr size_t PART_OFS = NK_OFS + 384;              // (unused, legacy)
constexpr size_t ATTN_OFS = PART_OFS + (size_t)SPLITS * 12 * 1024;  // [12][1024]
constexpr size_t W2_OFS   = ATTN_OFS + 12288;          // [2][192][192]
constexpr size_t XOFF_OFS = 11330304;                  // [9216][1728] bf16 == offc partials [12][663552] f32
constexpr size_t WBT_OFS  = XOFF_OFS + 7962624;        // [192][1728] bf16
// total ws: 19,458,816 floats = 77.8 MB (unchanged)

typedef __attribute__((ext_vector_type(8))) short bf16x8;
typedef __attribute__((ext_vector_type(4))) float f32x4;

__device__ __forceinline__ unsigned bf16rne(float f) {
  unsigned u = __float_as_uint(f);
  return (u + 0x7fffu + ((u >> 16) & 1u)) >> 16;
}
__device__ __forceinline__ float bf2f(unsigned hw) {
  return __uint_as_float(hw << 16);
}

// ---------------------------------------------------------------- K1a: offset conv partials
__global__ __launch_bounds__(192) void k_offc_part(
    const float* __restrict__ x, const float* __restrict__ pw,
    float* __restrict__ part)
{
  __shared__ float band[16 * 4 * 98];          // [cc][row 4][col 98]
  int blk = blockIdx.x;
  int csp = blk % 12;
  int rem = blk / 12;
  int b  = rem / 48;
  int r0 = (rem % 48) * 2;
  int c0 = csp * 16;
  int t  = threadIdx.x;
  int r = t / 96, w = t % 96;

  for (int i = 0; i < 33; ++i) {
    int e = t + i * 192;
    if (e < 6272) {
      int cc = e / 392, r2 = e % 392;
      int row = r2 / 98, col = r2 % 98;
      int gr = r0 + row - 1, gc = col - 1;
      float v = 0.f;
      if (gr >= 0 && gr < 96 && gc >= 0 && gc < 96)
        v = x[((b * 192 + c0 + cc) * 96 + gr) * 96 + gc];
      band[cc * 392 + row * 98 + col] = v;
    }
  }
  __syncthreads();

  float acc[18] = {};
#pragma unroll 4
  for (int cc = 0; cc < 16; ++cc) {
    float bv[9];
#pragma unroll
    for (int ki = 0; ki < 3; ++ki)
#pragma unroll
      for (int kj = 0; kj < 3; ++kj)
        bv[ki * 3 + kj] = band[cc * 392 + (r + ki) * 98 + w + kj];
#pragma unroll
    for (int o = 0; o < 18; ++o) {
      float w9[9];
#pragma unroll
      for (int kk = 0; kk < 9; ++kk)        // wave-uniform -> s_load
        w9[kk] = pw[(o * 192 + c0 + cc) * 9 + kk];
#pragma unroll
      for (int kk = 0; kk < 9; ++kk)
        acc[o] += w9[kk] * bv[kk];
    }
  }
  float* dst = &part[(size_t)csp * 663552 + ((size_t)(b * 18) * 96 + r0 + r) * 96 + w];
#pragma unroll
  for (int o = 0; o < 18; ++o)
    dst[(size_t)o * 9216] = acc[o];
}

// ---------------------------------------------------------------- K1b: reduce partials + bias
__global__ __launch_bounds__(256) void k_offc_red(
    const float4* __restrict__ part4, const float* __restrict__ pb,
    float4* __restrict__ off4)
{
  int i4 = blockIdx.x * 256 + threadIdx.x;
  if (i4 >= 165888) return;
  int o = ((i4 * 4) / 9216) % 18;
  float bb = pb[o];
  float4 s = {bb, bb, bb, bb};
  for (int sp = 0; sp < 12; ++sp) {
    float4 v = part4[(size_t)sp * 165888 + i4];
    s.x += v.x; s.y += v.y; s.z += v.z; s.w += v.w;
  }
  off4[i4] = s;
}

// ---------------------------------------------------------------- K2a: fp32->bf16 converters
__global__ __launch_bounds__(256) void k_cvtw(
    const float4* __restrict__ dw4, uint2* __restrict__ out, int n4)
{
  int i = blockIdx.x * 256 + threadIdx.x;
  if (i < n4) {
    float4 v = dw4[i];
    out[i] = uint2{bf16rne(v.x) | (bf16rne(v.y) << 16),
                   bf16rne(v.z) | (bf16rne(v.w) << 16)};
  }
}
// qkvw rows 192..575 -> wq[384][192] bf16
__global__ __launch_bounds__(256) void k_cvtqkvw(
    const float* __restrict__ qkvw, unsigned* __restrict__ wqu)
{
  int i = blockIdx.x * 256 + threadIdx.x;
  if (i < 36864)
    wqu[i] = bf16rne(qkvw[36864 + 2 * i]) | (bf16rne(qkvw[36864 + 2 * i + 1]) << 16);
}

// ---------------------------------------------------------------- K3: [k;v] = Wqkv(bf16) @ x(bf16) via MFMA
__global__ __launch_bounds__(64) void k_qkv_mfma(
    const float* __restrict__ x, const unsigned short* __restrict__ wq,
    unsigned short* __restrict__ kbf, float* __restrict__ vbuf)
{
  __shared__ unsigned Bl[32 * 100];
  int id = blockIdx.x;
  int b  = id / 2304;
  int rem = id % 2304;
  int og = rem & 7;
  int pt = rem >> 3;
  int pix0 = pt * 32;
  int l = threadIdx.x;
  int lo = l & 15, hi = l >> 4;

  const float* xb = x + (size_t)b * 192 * 9216 + pix0;
  for (int i = 0; i < 48; ++i) {
    int e = l + i * 64;
    int cp = e >> 5, px = e & 31;
    float x0 = xb[(size_t)(2 * cp) * 9216 + px];
    float x1 = xb[(size_t)(2 * cp + 1) * 9216 + px];
    Bl[px * 100 + cp] = bf16rne(x0) | (bf16rne(x1) << 16);
  }
  __syncthreads();

  const unsigned short* A0 = wq + (og * 48 + lo) * 192 + hi * 8;
  const unsigned short* A1 = A0 + 16 * 192;
  const unsigned short* A2 = A0 + 32 * 192;
  const unsigned* B0 = &Bl[lo * 100 + hi * 4];
  const unsigned* B1 = &Bl[(16 + lo) * 100 + hi * 4];
  f32x4 acc00 = {}, acc01 = {}, acc10 = {}, acc11 = {}, acc20 = {}, acc21 = {};
#pragma unroll
  for (int ks = 0; ks < 6; ++ks) {
    bf16x8 av0 = *(const bf16x8*)(A0 + ks * 32);
    bf16x8 av1 = *(const bf16x8*)(A1 + ks * 32);
    bf16x8 av2 = *(const bf16x8*)(A2 + ks * 32);
    bf16x8 bv0 = *(const bf16x8*)(B0 + ks * 16);
    bf16x8 bv1 = *(const bf16x8*)(B1 + ks * 16);
    acc00 = __builtin_amdgcn_mfma_f32_16x16x32_bf16(av0, bv0, acc00, 0, 0, 0);
    acc01 = __builtin_amdgcn_mfma_f32_16x16x32_bf16(av0, bv1, acc01, 0, 0, 0);
    acc10 = __builtin_amdgcn_mfma_f32_16x16x32_bf16(av1, bv0, acc10, 0, 0, 0);
    acc11 = __builtin_amdgcn_mfma_f32_16x16x32_bf16(av1, bv1, acc11, 0, 0, 0);
    acc20 = __builtin_amdgcn_mfma_f32_16x16x32_bf16(av2, bv0, acc20, 0, 0, 0);
    acc21 = __builtin_amdgcn_mfma_f32_16x16x32_bf16(av2, bv1, acc21, 0, 0, 0);
  }
  f32x4* accs[3][2] = {{&acc00, &acc01}, {&acc10, &acc11}, {&acc20, &acc21}};
#pragma unroll
  for (int fo = 0; fo < 3; ++fo)
#pragma unroll
    for (int fp = 0; fp < 2; ++fp)
#pragma unroll
      for (int r = 0; r < 4; ++r) {
        int o = og * 48 + fo * 16 + hi * 4 + r;
        int px = pix0 + fp * 16 + lo;
        float vv = (*accs[fo][fp])[r];
        if (o < 192)
          kbf[(size_t)(b * 192 + o) * 9216 + px] = (unsigned short)bf16rne(vv);
        else
          vbuf[(size_t)(b * 192 + (o - 192)) * 9216 + px] = vv;
      }
}

// ---------------------------------------------------------------- K4: direct-gather sample -> xofft[pix][k] bf16
// grid 1152 = 288 tiles x 4 csplit(48ch); block 256 = 32 px x 8 cg x 6 ch.
// R9: results staged in LDS [32px][217dw pad], then written out COALESCED
// (864 B contiguous per pixel chunk). Per-tap table values hoisted.
__global__ __launch_bounds__(256) void k_sample(
    const float* __restrict__ x, const float* __restrict__ off,
    unsigned* __restrict__ xoffu, int b)
{
  __shared__ float twt[4][288];
  __shared__ int   tof[4][288];
  __shared__ unsigned sbuf[32 * 217];        // [px][216 dw + 1 pad]
  int blk = blockIdx.x;
  int csp = blk & 3;
  int tile = blk >> 2;
  int h  = tile / 3;
  int w0 = (tile % 3) * 32;
  int t  = threadIdx.x;

  for (int e = t; e < 288; e += 256) {
    int n = e >> 5, pix = e & 31;
    int ki = n / 3, kj = n % 3;
    int w = w0 + pix;
    float ox = off[((b * 18 + n) * 96 + h) * 96 + w];
    float oy = off[((b * 18 + 9 + n) * 96 + h) * 96 + w];
    float px = (float)(h + ki) + ox;
    float py = (float)(w + kj) + oy;
    float fx = floorf(px), fy = floorf(py);
    int qx0 = max(0, min(97, (int)fx));
    int qx1 = max(0, min(97, (int)fx + 1));
    int qy0 = max(0, min(97, (int)fy));
    int qy1 = max(0, min(97, (int)fy + 1));
    float pxc = fminf(fmaxf(px, 0.f), 97.f);
    float pyc = fminf(fmaxf(py, 0.f), 97.f);
    float wx0 = 1.f + ((float)qx0 - pxc);
    float wx1 = 1.f - ((float)qx1 - pxc);
    float wy0 = 1.f + ((float)qy0 - pyc);
    float wy1 = 1.f - ((float)qy1 - pyc);
    int X0 = qx0 - 1, X1 = qx1 - 1, Y0 = qy0 - 1, Y1 = qy1 - 1;
    bool vX0 = (unsigned)X0 < 96u, vX1 = (unsigned)X1 < 96u;
    bool vY0 = (unsigned)Y0 < 96u, vY1 = (unsigned)Y1 < 96u;
    twt[0][e] = (vX0 && vY0) ? wx0 * wy0 : 0.f;
    tof[0][e] = (vX0 && vY0) ? X0 * 96 + Y0 : 0;
    twt[1][e] = (vX1 && vY1) ? wx1 * wy1 : 0.f;
    tof[1][e] = (vX1 && vY1) ? X1 * 96 + Y1 : 0;
    twt[2][e] = (vX0 && vY1) ? wx0 * wy1 : 0.f;
    tof[2][e] = (vX0 && vY1) ? X0 * 96 + Y1 : 0;
    twt[3][e] = (vX1 && vY0) ? wx1 * wy0 : 0.f;
    tof[3][e] = (vX1 && vY0) ? X1 * 96 + Y0 : 0;
  }
  __syncthreads();

  int px = t & 31, cg = t >> 5;              // 8 groups x 6 channels
  int c0 = csp * 48 + cg * 6;
  const float* bas = x + (size_t)(b * 192 + c0) * 9216;
  unsigned short* sb = (unsigned short*)&sbuf[px * 217];
#pragma unroll
  for (int n = 0; n < 9; ++n) {
    int e2 = n * 32 + px;
    float wlt = twt[0][e2], wrb = twt[1][e2], wlb = twt[2][e2], wrt = twt[3][e2];
    int olt = tof[0][e2], orb = tof[1][e2], olb = tof[2][e2], ort = tof[3][e2];
#pragma unroll
    for (int cc = 0; cc < 6; ++cc) {
      const float* bc = bas + (size_t)cc * 9216;
      float v = wlt * bc[olt] + wrb * bc[orb] + wlb * bc[olb] + wrt * bc[ort];
      sb[cg * 54 + cc * 9 + n] = (unsigned short)bf16rne(v);
    }
  }
  __syncthreads();
  // coalesced writeout: 32 px x 216 dwords; per-pixel chunk 864 B contiguous
  unsigned basepix = (unsigned)(h * 96 + w0);
#pragma unroll
  for (int i = 0; i < 27; ++i) {
    int e = t + i * 256;
    int p2 = e / 216, o = e % 216;
    xoffu[((basepix + p2) * 1728u + (unsigned)csp * 432u) / 2 + o] = sbuf[p2 * 217 + o];
  }
}

// ---------------------------------------------------------------- K5: q = W(bf16) @ xofft(bf16), MFMA; q stored bf16
__global__ __launch_bounds__(64) void k_dgemm(
    const unsigned short* __restrict__ xofft, const unsigned short* __restrict__ wbt,
    unsigned short* __restrict__ qbf, int b)
{
  int blk = blockIdx.x;
  int og = blk & 3;
  int pt = blk >> 2;
  int l  = threadIdx.x;
  int lo = l & 15, hi = l >> 4;
  const char* X = (const char*)xofft;
  const char* W = (const char*)wbt;
  size_t a0 = ((size_t)(og * 48 + lo)      * 1728 + hi * 8) * 2;
  size_t a1 = ((size_t)(og * 48 + 16 + lo) * 1728 + hi * 8) * 2;
  size_t a2 = ((size_t)(og * 48 + 32 + lo) * 1728 + hi * 8) * 2;
  size_t b0 = ((size_t)(pt * 32 + lo)      * 1728 + hi * 8) * 2;
  size_t b1 = ((size_t)(pt * 32 + 16 + lo) * 1728 + hi * 8) * 2;
  f32x4 acc00 = {}, acc01 = {}, acc10 = {}, acc11 = {}, acc20 = {}, acc21 = {};
#pragma unroll 2
  for (int k0 = 0; k0 < 3456; k0 += 64) {
    bf16x8 av0 = *(const bf16x8*)(W + a0 + k0);
    bf16x8 av1 = *(const bf16x8*)(W + a1 + k0);
    bf16x8 av2 = *(const bf16x8*)(W + a2 + k0);
    bf16x8 bv0 = *(const bf16x8*)(X + b0 + k0);
    bf16x8 bv1 = *(const bf16x8*)(X + b1 + k0);
    acc00 = __builtin_amdgcn_mfma_f32_16x16x32_bf16(av0, bv0, acc00, 0, 0, 0);
    acc01 = __builtin_amdgcn_mfma_f32_16x16x32_bf16(av0, bv1, acc01, 0, 0, 0);
    acc10 = __builtin_amdgcn_mfma_f32_16x16x32_bf16(av1, bv0, acc10, 0, 0, 0);
    acc11 = __builtin_amdgcn_mfma_f32_16x16x32_bf16(av1, bv1, acc11, 0, 0, 0);
    acc20 = __builtin_amdgcn_mfma_f32_16x16x32_bf16(av2, bv0, acc20, 0, 0, 0);
    acc21 = __builtin_amdgcn_mfma_f32_16x16x32_bf16(av2, bv1, acc21, 0, 0, 0);
  }
  f32x4* accs[3][2] = {{&acc00, &acc01}, {&acc10, &acc11}, {&acc20, &acc21}};
#pragma unroll
  for (int fo = 0; fo < 3; ++fo)
#pragma unroll
    for (int fp = 0; fp < 2; ++fp)
#pragma unroll
      for (int r = 0; r < 4; ++r)
        qbf[(size_t)(b * 192 + og * 48 + fo * 16 + hi * 4 + r) * 9216
            + pt * 32 + fp * 16 + lo] = (unsigned short)bf16rne((*accs[fo][fp])[r]);
}

// ---------------------------------------------------------------- K6: inv L2 norms from bf16 rows
__global__ __launch_bounds__(256) void k_norms(
    const unsigned short* __restrict__ qbf, const unsigned short* __restrict__ kbf,
    float* __restrict__ nq, float* __restrict__ nk)
{
  __shared__ float red[4];
  int blk = blockIdx.x;
  int which = blk / 384, r = blk % 384;
  const uint4* s4 = (const uint4*)((which ? kbf : qbf) + (size_t)r * 9216);
  int t = threadIdx.x;
  float s = 0.f;
  for (int i = t; i < 1152; i += 256) {
    uint4 v = s4[i];
    unsigned ws_[4] = {v.x, v.y, v.z, v.w};
#pragma unroll
    for (int j = 0; j < 4; ++j) {
      float a = bf2f(ws_[j] & 0xffffu);
      float bq = __uint_as_float(ws_[j] & 0xffff0000u);
      s += a * a + bq * bq;
    }
  }
#pragma unroll
  for (int o = 32; o; o >>= 1) s += __shfl_xor(s, o);
  if ((t & 63) == 0) red[t >> 6] = s;
  __syncthreads();
  if (t == 0) {
    float tot = red[0] + red[1] + red[2] + red[3];
    (which ? nk : nq)[r] = 1.f / fmaxf(sqrtf(tot), 1e-12f);
  }
}

// ---------------------------------------------------------------- K7: Gram partials via MFMA
__global__ __launch_bounds__(64) void k_gram_mfma(
    const unsigned short* __restrict__ qbf, const unsigned short* __restrict__ kbf,
    float* __restrict__ part2)
{
  int blk = blockIdx.x;
  int split = blk / 12, r = blk % 12;
  int b = r / 6, hh = r % 6;
  int n0 = split * 192;
  int l = threadIdx.x;
  int lo = l & 15, hi = l >> 4;
  const unsigned short* Q0 = qbf + (size_t)(b * 192 + hh * 32 + lo) * 9216 + n0 + hi * 8;
  const unsigned short* Q1 = Q0 + (size_t)16 * 9216;
  const unsigned short* K0 = kbf + (size_t)(b * 192 + hh * 32 + lo) * 9216 + n0 + hi * 8;
  const unsigned short* K1 = K0 + (size_t)16 * 9216;
  f32x4 g00 = {}, g01 = {}, g10 = {}, g11 = {};
#pragma unroll
  for (int ks = 0; ks < 6; ++ks) {
    bf16x8 qa0 = *(const bf16x8*)(Q0 + ks * 32);
    bf16x8 qa1 = *(const bf16x8*)(Q1 + ks * 32);
    bf16x8 kb0 = *(const bf16x8*)(K0 + ks * 32);
    bf16x8 kb1 = *(const bf16x8*)(K1 + ks * 32);
    g00 = __builtin_amdgcn_mfma_f32_16x16x32_bf16(qa0, kb0, g00, 0, 0, 0);
    g01 = __builtin_amdgcn_mfma_f32_16x16x32_bf16(qa0, kb1, g01, 0, 0, 0);
    g10 = __builtin_amdgcn_mfma_f32_16x16x32_bf16(qa1, kb0, g10, 0, 0, 0);
    g11 = __builtin_amdgcn_mfma_f32_16x16x32_bf16(qa1, kb1, g11, 0, 0, 0);
  }
  float* dst = part2 + ((size_t)split * 12 + r) * 1024;
  f32x4* gs[2][2] = {{&g00, &g01}, {&g10, &g11}};
#pragma unroll
  for (int fc = 0; fc < 2; ++fc)
#pragma unroll
    for (int fd = 0; fd < 2; ++fd)
#pragma unroll
      for (int rr = 0; rr < 4; ++rr)
        dst[(fc * 16 + hi * 4 + rr) * 32 + fd * 16 + lo] = (*gs[fc][fd])[rr];
}

// ---------------------------------------------------------------- K8: reduce + scale + softmax(d)
__global__ __launch_bounds__(1024) void k_softmax(
    const float* __restrict__ part2, const float* __restrict__ nq,
    const float* __restrict__ nk, const float* __restrict__ temp,
    float* __restrict__ attn)
{
  int bi = blockIdx.x;
  int b = bi / 6, h = bi % 6;
  int t = threadIdx.x;
  int c = t >> 5, d = t & 31;
  float val = 0.f;
  for (int s = 0; s < GSPL; ++s) val += part2[((size_t)s * 12 + bi) * 1024 + t];
  val *= nq[b * 192 + h * 32 + c] * nk[b * 192 + h * 32 + d] * temp[h];
  float m = val;
#pragma unroll
  for (int o = 16; o; o >>= 1) m = fmaxf(m, __shfl_xor(m, o));
  float e = expf(val - m);
  float s = e;
#pragma unroll
  for (int o = 16; o; o >>= 1) s += __shfl_xor(s, o);
  attn[(size_t)bi * 1024 + t] = e / s;
}

// ---------------------------------------------------------------- K9: W2 = proj . blockdiag(attn)
__global__ __launch_bounds__(256) void k_w2(
    const float* __restrict__ attn, const float* __restrict__ projw,
    float* __restrict__ w2)
{
  __shared__ float sa[32 * 33];
  int bi = blockIdx.x;
  int b = bi / 6, h = bi % 6;
  int t = threadIdx.x;
  for (int i = t; i < 1024; i += 256)
    sa[(i >> 5) * 33 + (i & 31)] = attn[(size_t)bi * 1024 + i];
  __syncthreads();
  for (int e = t; e < 6144; e += 256) {
    int o = e >> 5, d = e & 31;
    float s = 0.f;
#pragma unroll 8
    for (int ci = 0; ci < 32; ++ci)
      s += projw[o * 192 + h * 32 + ci] * sa[ci * 33 + d];
    w2[((size_t)b * 192 + o) * 192 + h * 32 + d] = s;
  }
}

// ---------------------------------------------------------------- K10: out = W2 @ v (fp32, unchanged)
__global__ __launch_bounds__(384) void k_out(
    const float* __restrict__ vbuf, const float* __restrict__ w2,
    float* __restrict__ out)
{
  __shared__ __align__(16) float Al[16 * 196];
  __shared__ __align__(16) float Bl[16 * 32];
  int blk = blockIdx.x;
  int b = blk / 288;
  int pix0 = (blk % 288) * 32;
  int t = threadIdx.x;
  int og = t >> 3, pg = t & 7;
  float acc[4][4] = {};
  float ra[8], rb2[2];
#pragma unroll
  for (int i = 0; i < 8; ++i) {
    int e = t + i * 384;
    ra[i] = w2[(size_t)(b * 192 + (e >> 4)) * 192 + (e & 15)];
  }
#pragma unroll
  for (int i = 0; i < 2; ++i) {
    int e = t + i * 384;
    rb2[i] = (e < 512) ? vbuf[(size_t)(b * 192 + (e >> 5)) * 9216 + pix0 + (e & 31)] : 0.f;
  }
  for (int c0 = 0; c0 < 192; c0 += 16) {
#pragma unroll
    for (int i = 0; i < 8; ++i) {
      int e = t + i * 384;
      Al[(e & 15) * 196 + (e >> 4)] = ra[i];
    }
#pragma unroll
    for (int i = 0; i < 2; ++i) {
      int e = t + i * 384;
      if (e < 512) Bl[e] = rb2[i];
    }
    __syncthreads();
    if (c0 + 16 < 192) {
#pragma unroll
      for (int i = 0; i < 8; ++i) {
        int e = t + i * 384;
        ra[i] = w2[(size_t)(b * 192 + (e >> 4)) * 192 + c0 + 16 + (e & 15)];
      }
#pragma unroll
      for (int i = 0; i < 2; ++i) {
        int e = t + i * 384;
        rb2[i] = (e < 512) ? vbuf[(size_t)(b * 192 + c0 + 16 + (e >> 5)) * 9216 + pix0 + (e & 31)] : 0.f;
      }
    }
    const float4* B4 = (const float4*)Bl;
    const float4* A4 = (const float4*)Al;
#pragma unroll
    for (int k = 0; k < 16; ++k) {
      float4 bv = B4[k * 8 + pg];
      float4 va = A4[k * 49 + og];
      float av[4] = {va.x, va.y, va.z, va.w};
#pragma unroll
      for (int i = 0; i < 4; ++i) {
        acc[i][0] += av[i] * bv.x; acc[i][1] += av[i] * bv.y;
        acc[i][2] += av[i] * bv.z; acc[i][3] += av[i] * bv.w;
      }
    }
    __syncthreads();
  }
#pragma unroll
  for (int i = 0; i < 4; ++i) {
    int o = og * 4 + i;
    *(float4*)&out[(size_t)(b * 192 + o) * 9216 + pix0 + pg * 4]
        = {acc[i][0], acc[i][1], acc[i][2], acc[i][3]};
  }
}

// ----------------------------------------------------------------
extern "C" void kernel_launch(void* const* d_in, const int* in_sizes, int n_in,
                              void* d_out, int out_size, void* d_ws, size_t ws_size,
                              hipStream_t stream) {
  (void)in_sizes; (void)n_in; (void)out_size; (void)ws_size;
  const float* x     = (const float*)d_in[0];
  const float* pw    = (const float*)d_in[1];
  const float* pb    = (const float*)d_in[2];
  const float* dw    = (const float*)d_in[3];
  const float* qkvw  = (const float*)d_in[4];
  const float* projw = (const float*)d_in[5];
  const float* temp  = (const float*)d_in[6];
  float* ws   = (float*)d_ws;
  float* off  = ws + OFF_OFS;
  unsigned short* qbf = (unsigned short*)(ws + Q_OFS);
  unsigned*       wqu = (unsigned*)(ws + QKVWBF_OFS);
  unsigned short* wq  = (unsigned short*)wqu;
  unsigned short* kbf = (unsigned short*)(ws + K_OFS);
  float* part2 = ws + PART2_OFS;
  float* vb   = ws + V_OFS;
  float* nq   = ws + NQ_OFS;
  float* nk   = ws + NK_OFS;
  float* attn = ws + ATTN_OFS;
  float* w2   = ws + W2_OFS;
  float* opart = ws + XOFF_OFS;                 // offc partials, then xofft
  unsigned*       xoffu = (unsigned*)(ws + XOFF_OFS);
  unsigned short* xofft = (unsigned short*)xoffu;
  unsigned short* wbt   = (unsigned short*)(ws + WBT_OFS);
  float* out  = (float*)d_out;

  k_offc_part  <<<dim3(1152), dim3(192), 0, stream>>>(x, pw, opart);
  k_offc_red   <<<dim3(648),  dim3(256), 0, stream>>>((const float4*)opart, pb, (float4*)off);
  k_cvtw       <<<dim3(324),  dim3(256), 0, stream>>>((const float4*)dw, (uint2*)wbt, 82944);
  k_cvtqkvw    <<<dim3(144),  dim3(256), 0, stream>>>(qkvw, wqu);
  k_qkv_mfma   <<<dim3(4608), dim3(64),  0, stream>>>(x, wq, kbf, vb);
  for (int b = 0; b < 2; ++b) {
    k_sample   <<<dim3(1152), dim3(256), 0, stream>>>(x, off, xoffu, b);
    k_dgemm    <<<dim3(1152), dim3(64),  0, stream>>>(xofft, wbt, qbf, b);
  }
  k_norms      <<<dim3(768),  dim3(256), 0, stream>>>(qbf, kbf, nq, nk);
  k_gram_mfma  <<<dim3(576),  dim3(64),  0, stream>>>(qbf, kbf, part2);
  k_softmax    <<<dim3(12),   dim3(1024),0, stream>>>(part2, nq, nk, temp, attn);
  k_w2         <<<dim3(12),   dim3(256), 0, stream>>>(attn, projw, w2);
  k_out        <<<dim3(576),  dim3(384), 0, stream>>>(vb, w2, out);
}